// Round 8
// baseline (443.664 us; speedup 1.0000x reference)
//
#include <hip/hip_runtime.h>
#include <math.h>

#define NN 10000
#define NE 160000
#define NB 128
#define NH 4
#define DOUT 512
#define NEG 0.2f
#define CNT_BLKS ((NE + 255) / 256)    // 625 (fill blocks)

typedef __attribute__((ext_vector_type(8))) short short8;
typedef __attribute__((ext_vector_type(4))) float f32x4;
typedef __attribute__((ext_vector_type(4))) unsigned short us4;

__device__ __forceinline__ float leakyf(float v){ return fmaxf(v, NEG*v); }
__device__ __forceinline__ void fma4(float4& a, const float4 v, float w){
  a.x += v.x*w; a.y += v.y*w; a.z += v.z*w; a.w += v.w*w;
}
__device__ __forceinline__ unsigned short f2bf(float f){
  unsigned int u = __float_as_uint(f);
  u += 0x7FFFu + ((u >> 16) & 1u);
  return (unsigned short)(u >> 16);
}
__device__ __forceinline__ float bf2f(unsigned short h){
  return __uint_as_float(((unsigned int)h) << 16);
}
__device__ __forceinline__ void split2(float v, unsigned short& h, unsigned short& l){
  h = f2bf(v);
  l = f2bf(v - bf2f(h));
}
__device__ __forceinline__ void store_hl(unsigned short* H, unsigned short* L,
                                         size_t base, float4 v){
  us4 h, l; unsigned short hh, ll;
  split2(v.x, hh, ll); h[0]=hh; l[0]=ll;
  split2(v.y, hh, ll); h[1]=hh; l[1]=ll;
  split2(v.z, hh, ll); h[2]=hh; l[2]=ll;
  split2(v.w, hh, ll); h[3]=hh; l[3]=ll;
  *(us4*)&H[base] = h;
  *(us4*)&L[base] = l;
}
__device__ __forceinline__ void gl_lds16(const unsigned short* g, unsigned short* l){
  __builtin_amdgcn_global_load_lds(
      (const __attribute__((address_space(1))) unsigned int*)g,
      (__attribute__((address_space(3))) unsigned int*)l, 16, 0, 0);
}

// ============ conversions descriptor (weights only) ============
struct AllConv {
  const float* src[7];
  unsigned short* dh[7];
  unsigned short* dl[7];
  int K[7], Mm[7], Kp[7], tot[7];
};

// ===== single-block scan: degree count (direct from dst, LDS histogram) +
//       rowptr/dinv/cursor/apre/starts/perm + pool bookkeeping (gexp/gdone) =====
__global__ __launch_bounds__(1024) void k_scan_all(
    const int* __restrict__ dst, const int* __restrict__ batch,
    int* __restrict__ rowptr, float* __restrict__ dinv,
    int* __restrict__ cursor, float* __restrict__ apre,
    int* __restrict__ starts, int* __restrict__ perm,
    int* __restrict__ gexp, int* __restrict__ gdone, float* __restrict__ outp){
  __shared__ int sh[NN];      // 40 KB
  __shared__ int pref[1024];
  __shared__ int hist[512];
  __shared__ int hbase[512];
  int t = threadIdx.x;
  for (int i = t; i < NN; i += 1024) sh[i] = 0;
  if (t < 512) hist[t] = 0;
  if (t <= NB){
    int lo = 0, hi = NN;
    while (lo < hi){ int mid = (lo + hi) >> 1; if (batch[mid] < t) lo = mid + 1; else hi = mid; }
    starts[t] = lo;
  }
  __syncthreads();
  // direct edge count into LDS
  for (int i = t; i < NE; i += 1024) atomicAdd(&sh[dst[i]], 1);
  __syncthreads();
  int base = t*10;
  int csum = 0;
#pragma unroll
  for (int k = 0; k < 10; k++){
    int i = base + k;
    if (i < NN){
      csum += sh[i];
      atomicAdd(&hist[511 - min(sh[i], 511)], 1);   // descending degree bins
    }
  }
  pref[t] = csum; __syncthreads();
  int horig = (t < 512) ? hist[t] : 0;
  for (int o = 1; o < 1024; o <<= 1){
    int v = (t >= o) ? pref[t - o] : 0;
    __syncthreads();
    pref[t] += v;
    __syncthreads();
  }
  for (int o = 1; o < 512; o <<= 1){
    int v = 0;
    if (t < 512 && t >= o) v = hist[t - o];
    __syncthreads();
    if (t < 512 && t >= o) hist[t] += v;
    __syncthreads();
  }
  if (t < 512) hbase[t] = hist[t] - horig;   // exclusive prefix -> scatter cursor
  __syncthreads();
  int run = pref[t] - csum;   // exclusive prefix of degrees
#pragma unroll
  for (int k = 0; k < 10; k++){
    int i = base + k;
    if (i < NN){
      int c = sh[i];
      rowptr[i] = run;
      run += c;
      dinv[i] = rsqrtf((float)c + 1.f);
      cursor[i] = 0;
      apre[i] = 0.f;
      int pos = atomicAdd(&hbase[511 - min(c, 511)], 1);
      perm[pos] = i;
    }
  }
  if (t == 1023) rowptr[NN] = pref[1023];
  __syncthreads();
  // pool bookkeeping: expected contributor count per graph (mode3 blocks: 2 col-blocks
  // per 64-row block overlapping the graph); empty graphs get identity outputs now.
  if (t < NB){
    int b0 = starts[t], e0 = starts[t+1];
    gdone[t] = 0;
    gexp[t] = (e0 > b0) ? 2*(((e0-1) >> 6) - (b0 >> 6) + 1) : 0x7fffffff;
    if (e0 == b0){
      float4* o = (float4*)(outp + (size_t)t*4*DOUT);
      float4 z = make_float4(0.f,0.f,0.f,0.f);
      float4 ni = make_float4(-INFINITY,-INFINITY,-INFINITY,-INFINITY);
      for (int q = 0; q < 128; q++){ o[q]=z; o[128+q]=z; o[256+q]=ni; o[384+q]=z; }
    }
  }
}

// ===== merged: CSR fill (blocks [0,CNT_BLKS)) + weight conversions (rest) =====
__global__ void k_fill_conv(const int* __restrict__ src, const int* __restrict__ dst,
                            const int* __restrict__ rowptr, int* __restrict__ cursor,
                            int* __restrict__ colidx, AllConv a, int convTot){
  int bid = blockIdx.x;
  if (bid < CNT_BLKS){
    int e = bid*256 + threadIdx.x;
    if (e < NE){
      int d = dst[e];
      int pos = atomicAdd(&cursor[d], 1);
      colidx[rowptr[d] + pos] = src[e];
    }
  } else {
    int idx = (bid - CNT_BLKS)*256 + threadIdx.x;
    if (idx >= convTot) return;
    int j = 0;
    while (idx >= a.tot[j]){ idx -= a.tot[j]; j++; }
    int Kp = a.Kp[j], K = a.K[j], M = a.Mm[j];
    int kk = idx % Kp, m = idx / Kp;
    float v = (kk < K) ? a.src[j][(size_t)kk*M + m] : 0.f;
    unsigned short h, l; split2(v, h, l);
    a.dh[j][idx] = h; a.dl[j][idx] = l;
  }
}

// ===== GEMM: C[N,M] = (Ah+Al)[N,Kp] @ (Bh+Bl)^T, bf16x3, K-step 64.
//       mode==3 additionally runs fused attention-pooling via last-block pattern. =====
#define GBM 64
#define GBN 128
#define GBK 64
__global__ __launch_bounds__(256) void k_gemm_bf3(
    const unsigned short* __restrict__ Ah, const unsigned short* __restrict__ Al,
    const unsigned short* __restrict__ Bh, const unsigned short* __restrict__ Bl,
    float* __restrict__ C, int N, int Kp, int M, int mode,
    const float* __restrict__ bias, unsigned short* __restrict__ outH,
    unsigned short* __restrict__ outL,
    const float* __restrict__ a_s, const float* __restrict__ a_d,
    float* __restrict__ as_o, float* __restrict__ ad_o, int Cdim,
    const int* __restrict__ starts, const int* __restrict__ gexp,
    int* __restrict__ gdone, const float* __restrict__ xfull,
    float* __restrict__ outp){
  __shared__ unsigned short AsH[2*GBM*32], AsL[2*GBM*32];   // 8 KB each
  __shared__ unsigned short BsH[2*GBN*32], BsL[2*GBN*32];   // 16 KB each
  __shared__ float sred[2][GBM][4];
  __shared__ int winners[8];
  __shared__ int nwin;
  int gx = M / GBN;
  int gy = (N + GBM - 1) / GBM;
  const int G = 8;
  int bid = blockIdx.x;
  int full = gy / G;
  int bid_full = full * G * gx;
  int by, bx;
  if (bid < bid_full){
    int g = bid / (G*gx); int rem = bid % (G*gx);
    by = g*G + rem % G; bx = rem / G;
  } else {
    int rem = bid - bid_full; int rows = gy - full*G;
    by = full*G + rem % rows; bx = rem / rows;
  }
  int row0 = by * GBM, col0 = bx * GBN;
  int t = threadIdx.x;
  int w = t >> 6, L = t & 63;
  int lm = L & 15, lq = L >> 4;
  int wc = w * 32;

  int sr = L >> 2, sc = L & 3;
  int art = w*16 + sr;
  int ga  = (sc - ((art >> 1) & 3)) & 3;
  int agrow = min(row0 + art, N-1);
  int brt0 = w*16 + sr;
  int brt1 = (w+4)*16 + sr;
  int gb0 = (sc - ((brt0 >> 1) & 3)) & 3;
  int gb1 = (sc - ((brt1 >> 1) & 3)) & 3;
  int bgrow0 = col0 + brt0, bgrow1 = col0 + brt1;

  int rc = (lq + (lm >> 1)) & 3;
  int aoff[4], boff[2];
#pragma unroll
  for (int mi = 0; mi < 4; mi++) aoff[mi] = (mi*16 + lm)*32 + rc*8;
#pragma unroll
  for (int ni = 0; ni < 2; ni++) boff[ni] = (wc + ni*16 + lm)*32 + rc*8;

  f32x4 acc[4][2];
#pragma unroll
  for (int i = 0; i < 4; i++)
#pragma unroll
    for (int j = 0; j < 2; j++) acc[i][j] = (f32x4){0.f,0.f,0.f,0.f};

  int nk = Kp / GBK;
  for (int kt = 0; kt < nk; kt++){
    int k0 = kt * GBK;
    if (kt) __syncthreads();
#pragma unroll
    for (int h = 0; h < 2; h++){
      int kh = k0 + h*32;
      gl_lds16(&Ah[(size_t)agrow*Kp + kh + ga*8],  &AsH[h*2048 + w*512]);
      gl_lds16(&Al[(size_t)agrow*Kp + kh + ga*8],  &AsL[h*2048 + w*512]);
      gl_lds16(&Bh[(size_t)bgrow0*Kp + kh + gb0*8], &BsH[h*4096 + w*512]);
      gl_lds16(&Bh[(size_t)bgrow1*Kp + kh + gb1*8], &BsH[h*4096 + (w+4)*512]);
      gl_lds16(&Bl[(size_t)bgrow0*Kp + kh + gb0*8], &BsL[h*4096 + w*512]);
      gl_lds16(&Bl[(size_t)bgrow1*Kp + kh + gb1*8], &BsL[h*4096 + (w+4)*512]);
    }
    __syncthreads();

#pragma unroll
    for (int h = 0; h < 2; h++){
      short8 ah[4], al[4], bh[2], bl[2];
#pragma unroll
      for (int mi = 0; mi < 4; mi++){
        ah[mi] = *(const short8*)&AsH[h*2048 + aoff[mi]];
        al[mi] = *(const short8*)&AsL[h*2048 + aoff[mi]];
      }
#pragma unroll
      for (int ni = 0; ni < 2; ni++){
        bh[ni] = *(const short8*)&BsH[h*4096 + boff[ni]];
        bl[ni] = *(const short8*)&BsL[h*4096 + boff[ni]];
      }
#pragma unroll
      for (int mi = 0; mi < 4; mi++)
#pragma unroll
        for (int ni = 0; ni < 2; ni++){
          acc[mi][ni] = __builtin_amdgcn_mfma_f32_16x16x32_bf16(ah[mi], bh[ni], acc[mi][ni], 0, 0, 0);
          acc[mi][ni] = __builtin_amdgcn_mfma_f32_16x16x32_bf16(ah[mi], bl[ni], acc[mi][ni], 0, 0, 0);
          acc[mi][ni] = __builtin_amdgcn_mfma_f32_16x16x32_bf16(al[mi], bh[ni], acc[mi][ni], 0, 0, 0);
        }
    }
  }
  if (mode == 1){
    // relu + bias; store H/L (GEMM2 A-operand) AND fp32 copy (gat residual read)
#pragma unroll
    for (int mi = 0; mi < 4; mi++)
#pragma unroll
      for (int ni = 0; ni < 2; ni++){
#pragma unroll
        for (int r = 0; r < 4; r++){
          int row = row0 + mi*16 + lq*4 + r;
          int col = col0 + wc + ni*16 + lm;
          if (row < N){
            float v = fmaxf(acc[mi][ni][r] + bias[col], 0.f);
            unsigned short hh, ll; split2(v, hh, ll);
            outH[(size_t)row*M + col] = hh;
            outL[(size_t)row*M + col] = ll;
            C[(size_t)row*M + col] = v;
          }
        }
      }
  } else if (mode != 3){
#pragma unroll
    for (int mi = 0; mi < 4; mi++)
#pragma unroll
      for (int ni = 0; ni < 2; ni++){
#pragma unroll
        for (int r = 0; r < 4; r++){
          int row = row0 + mi*16 + lq*4 + r;
          int col = col0 + wc + ni*16 + lm;
          if (row < N) C[(size_t)row*M + col] = acc[mi][ni][r];
        }
      }
  }
  if (mode == 2){
    float sA0 = a_s[col0 + wc + lm], sA1 = a_s[col0 + wc + 16 + lm];
    float dA0 = a_d[col0 + wc + lm], dA1 = a_d[col0 + wc + 16 + lm];
#pragma unroll
    for (int mi = 0; mi < 4; mi++)
#pragma unroll
      for (int r = 0; r < 4; r++){
        float vs = acc[mi][0][r]*sA0 + acc[mi][1][r]*sA1;
        float vd = acc[mi][0][r]*dA0 + acc[mi][1][r]*dA1;
#pragma unroll
        for (int o = 1; o <= 8; o <<= 1){
          vs += __shfl_xor(vs, o);
          vd += __shfl_xor(vd, o);
        }
        if (lm == 0){
          int row = mi*16 + lq*4 + r;
          sred[0][row][w] = vs;
          sred[1][row][w] = vd;
        }
      }
    __syncthreads();
    if (t < GBM){
      int n = row0 + t;
      if (n < N){
        int wph = Cdim >> 5;
        int nheads = 4 / wph;
        for (int g = 0; g < nheads; g++){
          float ss = 0.f, dd = 0.f;
          for (int q = 0; q < wph; q++){
            ss += sred[0][t][g*wph + q];
            dd += sred[1][t][g*wph + q];
          }
          int hd = (col0 + g*wph*32) / Cdim;
          as_o[n*NH + hd] = ss;
          ad_o[n*NH + hd] = dd;
        }
      }
    }
  } else if (mode == 3){
    float b0 = bias[col0 + wc + lm], b1v = bias[col0 + wc + 16 + lm];
    float w0v = a_s[col0 + wc + lm], w1v = a_s[col0 + wc + 16 + lm];
#pragma unroll
    for (int mi = 0; mi < 4; mi++)
#pragma unroll
      for (int r = 0; r < 4; r++){
        float v = tanhf(acc[mi][0][r] + b0)*w0v + tanhf(acc[mi][1][r] + b1v)*w1v;
#pragma unroll
        for (int o = 1; o <= 8; o <<= 1) v += __shfl_xor(v, o);
        if (lm == 0) sred[0][mi*16 + lq*4 + r][w] = v;
      }
    __syncthreads();
    if (t < GBM){
      int n = row0 + t;
      if (n < N){
        float s = sred[0][t][0] + sred[0][t][1] + sred[0][t][2] + sred[0][t][3];
        atomicAdd(&as_o[n], s);
      }
    }
    // ---- fused attention pooling: last contributing block pools its graphs ----
    __syncthreads();
    __threadfence();
    if (t == 0){
      nwin = 0;
      int row1 = min(row0 + GBM, N);
      int glo = NB, ghi = -1;
      { int a2 = 0, b2 = NB-1;
        while (a2 <= b2){ int m2 = (a2+b2)>>1; if (starts[m2+1] > row0){ glo = m2; b2 = m2-1; } else a2 = m2+1; } }
      { int a2 = 0, b2 = NB-1;
        while (a2 <= b2){ int m2 = (a2+b2)>>1; if (starts[m2] < row1){ ghi = m2; a2 = m2+1; } else b2 = m2-1; } }
      for (int g = glo; g <= ghi && g < NB; g++){
        if (starts[g+1] > starts[g]){
          int old = atomicAdd(&gdone[g], 1);
          if (old == gexp[g]-1 && nwin < 8) winners[nwin++] = g;
        }
      }
    }
    __syncthreads();
    int nw = nwin;
    for (int wix = 0; wix < nw; wix++){
      int g = winners[wix];
      int gb = starts[g], ge = starts[g+1];
      float* red = (float*)AsH;                 // reuse staging LDS (done with it)
      float4* comb = (float4*)BsH;              // comb[3][2][128] = 12 KB < 16 KB
      float m = -INFINITY;
      for (int n = gb + t; n < ge; n += 256) m = fmaxf(m, as_o[n]);
      red[t] = m; __syncthreads();
      for (int o2 = 128; o2 > 0; o2 >>= 1){
        if (t < o2) red[t] = fmaxf(red[t], red[t + o2]);
        __syncthreads();
      }
      m = red[0]; __syncthreads();
      float s = 0.f;
      for (int n = gb + t; n < ge; n += 256) s += __expf(as_o[n] - m);
      red[t] = s; __syncthreads();
      for (int o2 = 128; o2 > 0; o2 >>= 1){
        if (t < o2) red[t] += red[t + o2];
        __syncthreads();
      }
      float inv = 1.f / (red[0] + 1e-8f);
      __syncthreads();
      int lf = t & 127, sl2 = t >> 7;           // 128 float4 feats × 2 node slices
      float4 sum = make_float4(0,0,0,0), wacc = make_float4(0,0,0,0);
      float4 mx = make_float4(-INFINITY,-INFINITY,-INFINITY,-INFINITY);
      for (int n = gb + sl2; n < ge; n += 2){
        float4 xv = *(const float4*)&xfull[(size_t)n*DOUT + lf*4];
        float pw = __expf(as_o[n] - m) * inv;
        sum.x += xv.x; sum.y += xv.y; sum.z += xv.z; sum.w += xv.w;
        mx.x = fmaxf(mx.x, xv.x); mx.y = fmaxf(mx.y, xv.y);
        mx.z = fmaxf(mx.z, xv.z); mx.w = fmaxf(mx.w, xv.w);
        fma4(wacc, xv, pw);
      }
      comb[(0*2 + sl2)*128 + lf] = wacc;
      comb[(1*2 + sl2)*128 + lf] = sum;
      comb[(2*2 + sl2)*128 + lf] = mx;
      __syncthreads();
      if (sl2 == 0){
        float4 w2 = comb[(0*2+1)*128+lf], s2 = comb[(1*2+1)*128+lf], m2 = comb[(2*2+1)*128+lf];
        wacc.x += w2.x; wacc.y += w2.y; wacc.z += w2.z; wacc.w += w2.w;
        sum.x += s2.x; sum.y += s2.y; sum.z += s2.z; sum.w += s2.w;
        mx.x = fmaxf(mx.x, m2.x); mx.y = fmaxf(mx.y, m2.y);
        mx.z = fmaxf(mx.z, m2.z); mx.w = fmaxf(mx.w, m2.w);
        float ic = 1.f / fmaxf((float)(ge - gb), 1.f);
        float4* o = (float4*)(outp + (size_t)g*4*DOUT);
        o[lf]       = wacc;
        o[128 + lf] = make_float4(sum.x*ic, sum.y*ic, sum.z*ic, sum.w*ic);
        o[256 + lf] = mx;
        o[384 + lf] = sum;
      }
      __syncthreads();
    }
  }
}

// ===== GCN pre-agg layer 0: fp32 x0 direct, 8-way, degree-sorted =====
__global__ __launch_bounds__(256) void k_gcn_pre0(
    const float* __restrict__ x0, const float* __restrict__ dinv,
    const int* __restrict__ rowptr, const int* __restrict__ colidx,
    const int* __restrict__ perm,
    unsigned short* __restrict__ outH, unsigned short* __restrict__ outL){
  int t = threadIdx.x;
  int sub = t & 15;
  int gid = blockIdx.x*16 + (t >> 4);
  if (gid >= NN) return;
  int n = perm[gid];
  int f0 = sub*4;
  bool act = f0 < 36;
  int b = rowptr[n], e = rowptr[n+1];
  float dn = dinv[n];
  float4 a0 = make_float4(0,0,0,0), a1 = make_float4(0,0,0,0);
  float4 a2 = make_float4(0,0,0,0), a3 = make_float4(0,0,0,0);
  if (act){
    float4 sv = *(const float4*)&x0[(size_t)n*36 + f0];
    int j = b;
    for (; j + 7 < e; j += 8){
      int s0 = colidx[j],   s1 = colidx[j+1], s2 = colidx[j+2], s3 = colidx[j+3];
      int s4 = colidx[j+4], s5 = colidx[j+5], s6 = colidx[j+6], s7 = colidx[j+7];
      float w0 = dinv[s0], w1 = dinv[s1], w2 = dinv[s2], w3 = dinv[s3];
      float w4 = dinv[s4], w5 = dinv[s5], w6 = dinv[s6], w7 = dinv[s7];
      float4 v0 = *(const float4*)&x0[(size_t)s0*36 + f0];
      float4 v1 = *(const float4*)&x0[(size_t)s1*36 + f0];
      float4 v2 = *(const float4*)&x0[(size_t)s2*36 + f0];
      float4 v3 = *(const float4*)&x0[(size_t)s3*36 + f0];
      float4 v4 = *(const float4*)&x0[(size_t)s4*36 + f0];
      float4 v5 = *(const float4*)&x0[(size_t)s5*36 + f0];
      float4 v6 = *(const float4*)&x0[(size_t)s6*36 + f0];
      float4 v7 = *(const float4*)&x0[(size_t)s7*36 + f0];
      fma4(a0, v0, w0*dn); fma4(a1, v1, w1*dn);
      fma4(a2, v2, w2*dn); fma4(a3, v3, w3*dn);
      fma4(a0, v4, w4*dn); fma4(a1, v5, w5*dn);
      fma4(a2, v6, w6*dn); fma4(a3, v7, w7*dn);
    }
    for (; j + 3 < e; j += 4){
      int s0 = colidx[j], s1 = colidx[j+1], s2 = colidx[j+2], s3 = colidx[j+3];
      float w0 = dinv[s0], w1 = dinv[s1], w2 = dinv[s2], w3 = dinv[s3];
      float4 v0 = *(const float4*)&x0[(size_t)s0*36 + f0];
      float4 v1 = *(const float4*)&x0[(size_t)s1*36 + f0];
      float4 v2 = *(const float4*)&x0[(size_t)s2*36 + f0];
      float4 v3 = *(const float4*)&x0[(size_t)s3*36 + f0];
      fma4(a0, v0, w0*dn); fma4(a1, v1, w1*dn);
      fma4(a2, v2, w2*dn); fma4(a3, v3, w3*dn);
    }
    for (; j < e; j++){
      int s = colidx[j];
      float4 v = *(const float4*)&x0[(size_t)s*36 + f0];
      fma4(a0, v, dinv[s]*dn);
    }
    float4 acc = make_float4(a0.x+a1.x+a2.x+a3.x, a0.y+a1.y+a2.y+a3.y,
                             a0.z+a1.z+a2.z+a3.z, a0.w+a1.w+a2.w+a3.w);
    float dn2 = dn*dn;
    acc.x += sv.x*dn2; acc.y += sv.y*dn2; acc.z += sv.z*dn2; acc.w += sv.w*dn2;
    store_hl(outH, outL, (size_t)n*64 + f0, acc);
  } else {
    store_hl(outH, outL, (size_t)n*64 + f0, make_float4(0,0,0,0));
  }
}

// ===== GCN pre-agg (layers 1..2): fp32 input (xf), 8-way, degree-sorted =====
__global__ __launch_bounds__(256) void k_gcn_pre(
    const float* __restrict__ xf, const float* __restrict__ dinv,
    const int* __restrict__ rowptr, const int* __restrict__ colidx,
    const int* __restrict__ perm,
    unsigned short* __restrict__ outH, unsigned short* __restrict__ outL,
    int Kp, int nchunk){
  int bid = blockIdx.x;
  int chunk = bid % nchunk, grp = bid / nchunk;
  int t = threadIdx.x;
  int sub = t & 15;
  int gid = grp*16 + (t >> 4);
  if (gid >= NN) return;
  int n = perm[gid];
  int f0 = chunk*64 + sub*4;
  int b = rowptr[n], e = rowptr[n+1];
  float dn = dinv[n];
  float4 sv = *(const float4*)&xf[(size_t)n*Kp + f0];
  float4 a0 = make_float4(0,0,0,0), a1 = make_float4(0,0,0,0);
  float4 a2 = make_float4(0,0,0,0), a3 = make_float4(0,0,0,0);
  int j = b;
  for (; j + 7 < e; j += 8){
    int s0 = colidx[j],   s1 = colidx[j+1], s2 = colidx[j+2], s3 = colidx[j+3];
    int s4 = colidx[j+4], s5 = colidx[j+5], s6 = colidx[j+6], s7 = colidx[j+7];
    float w0 = dinv[s0], w1 = dinv[s1], w2 = dinv[s2], w3 = dinv[s3];
    float w4 = dinv[s4], w5 = dinv[s5], w6 = dinv[s6], w7 = dinv[s7];
    float4 v0 = *(const float4*)&xf[(size_t)s0*Kp + f0];
    float4 v1 = *(const float4*)&xf[(size_t)s1*Kp + f0];
    float4 v2 = *(const float4*)&xf[(size_t)s2*Kp + f0];
    float4 v3 = *(const float4*)&xf[(size_t)s3*Kp + f0];
    float4 v4 = *(const float4*)&xf[(size_t)s4*Kp + f0];
    float4 v5 = *(const float4*)&xf[(size_t)s5*Kp + f0];
    float4 v6 = *(const float4*)&xf[(size_t)s6*Kp + f0];
    float4 v7 = *(const float4*)&xf[(size_t)s7*Kp + f0];
    fma4(a0, v0, w0*dn); fma4(a1, v1, w1*dn);
    fma4(a2, v2, w2*dn); fma4(a3, v3, w3*dn);
    fma4(a0, v4, w4*dn); fma4(a1, v5, w5*dn);
    fma4(a2, v6, w6*dn); fma4(a3, v7, w7*dn);
  }
  for (; j + 3 < e; j += 4){
    int s0 = colidx[j], s1 = colidx[j+1], s2 = colidx[j+2], s3 = colidx[j+3];
    float w0 = dinv[s0], w1 = dinv[s1], w2 = dinv[s2], w3 = dinv[s3];
    float4 v0 = *(const float4*)&xf[(size_t)s0*Kp + f0];
    float4 v1 = *(const float4*)&xf[(size_t)s1*Kp + f0];
    float4 v2 = *(const float4*)&xf[(size_t)s2*Kp + f0];
    float4 v3 = *(const float4*)&xf[(size_t)s3*Kp + f0];
    fma4(a0, v0, w0*dn); fma4(a1, v1, w1*dn);
    fma4(a2, v2, w2*dn); fma4(a3, v3, w3*dn);
  }
  for (; j < e; j++){
    int s = colidx[j];
    float4 v = *(const float4*)&xf[(size_t)s*Kp + f0];
    fma4(a0, v, dinv[s]*dn);
  }
  float4 acc = make_float4(a0.x+a1.x+a2.x+a3.x, a0.y+a1.y+a2.y+a3.y,
                           a0.z+a1.z+a2.z+a3.z, a0.w+a1.w+a2.w+a3.w);
  float dn2 = dn*dn;
  acc.x += sv.x*dn2; acc.y += sv.y*dn2; acc.z += sv.z*dn2; acc.w += sv.w*dn2;
  store_hl(outH, outL, (size_t)n*Kp + f0, acc);
}

// ===== GAT gather: fixed-shift softmax, fp32 residual, degree-sorted =====
__global__ __launch_bounds__(256) void k_gat_gather(
    const float* __restrict__ hg, const float* __restrict__ hf,
    const int* __restrict__ rowptr, const int* __restrict__ colidx,
    const int* __restrict__ perm,
    const float* __restrict__ as_, const float* __restrict__ ad_,
    const float* __restrict__ ab,
    unsigned short* __restrict__ outH, unsigned short* __restrict__ outL,
    float* __restrict__ xf,
    int M, int C, int nchunk){
  int bid = blockIdx.x;
  int chunk = bid % nchunk, grp = bid / nchunk;
  int t = threadIdx.x;
  int sub = t & 15;
  int gid = grp*16 + (t >> 4);
  if (gid >= NN) return;
  int n = perm[gid];
  int f0 = chunk*64 + sub*4;
  int hd = f0 / C;
  int b = rowptr[n], e = rowptr[n+1];
  int ai = n*NH + hd;
  float adn = ad_[ai];
  float sl = fminf(fmaxf(leakyf(as_[ai] + adn), -80.f), 80.f);
  float es = __expf(sl);
  // hoisted tail loads — latency hides under the edge loop
  float4 sv = *(const float4*)&hg[(size_t)n*M + f0];
  float4 hv = *(const float4*)&hf[(size_t)n*M + f0];
  float4 bb = *(const float4*)&ab[f0];
  float d = es;
  float4 a0 = make_float4(0,0,0,0), a1 = make_float4(0,0,0,0);
  float4 a2 = make_float4(0,0,0,0), a3 = make_float4(0,0,0,0);
  int j = b;
  for (; j + 7 < e; j += 8){
    int s0 = colidx[j],   s1 = colidx[j+1], s2 = colidx[j+2], s3 = colidx[j+3];
    int s4 = colidx[j+4], s5 = colidx[j+5], s6 = colidx[j+6], s7 = colidx[j+7];
    float l0 = leakyf(as_[s0*NH + hd] + adn), l1 = leakyf(as_[s1*NH + hd] + adn);
    float l2 = leakyf(as_[s2*NH + hd] + adn), l3 = leakyf(as_[s3*NH + hd] + adn);
    float l4 = leakyf(as_[s4*NH + hd] + adn), l5 = leakyf(as_[s5*NH + hd] + adn);
    float l6 = leakyf(as_[s6*NH + hd] + adn), l7 = leakyf(as_[s7*NH + hd] + adn);
    float4 v0 = *(const float4*)&hg[(size_t)s0*M + f0];
    float4 v1 = *(const float4*)&hg[(size_t)s1*M + f0];
    float4 v2 = *(const float4*)&hg[(size_t)s2*M + f0];
    float4 v3 = *(const float4*)&hg[(size_t)s3*M + f0];
    float4 v4 = *(const float4*)&hg[(size_t)s4*M + f0];
    float4 v5 = *(const float4*)&hg[(size_t)s5*M + f0];
    float4 v6 = *(const float4*)&hg[(size_t)s6*M + f0];
    float4 v7 = *(const float4*)&hg[(size_t)s7*M + f0];
    float w0 = __expf(fminf(fmaxf(l0,-80.f),80.f)), w1 = __expf(fminf(fmaxf(l1,-80.f),80.f));
    float w2 = __expf(fminf(fmaxf(l2,-80.f),80.f)), w3 = __expf(fminf(fmaxf(l3,-80.f),80.f));
    float w4 = __expf(fminf(fmaxf(l4,-80.f),80.f)), w5 = __expf(fminf(fmaxf(l5,-80.f),80.f));
    float w6 = __expf(fminf(fmaxf(l6,-80.f),80.f)), w7 = __expf(fminf(fmaxf(l7,-80.f),80.f));
    d += ((w0 + w1) + (w2 + w3)) + ((w4 + w5) + (w6 + w7));
    fma4(a0, v0, w0); fma4(a1, v1, w1);
    fma4(a2, v2, w2); fma4(a3, v3, w3);
    fma4(a0, v4, w4); fma4(a1, v5, w5);
    fma4(a2, v6, w6); fma4(a3, v7, w7);
  }
  for (; j < e; j++){
    int s = colidx[j];
    float l = leakyf(as_[s*NH + hd] + adn);
    float4 v = *(const float4*)&hg[(size_t)s*M + f0];
    float ww = __expf(fminf(fmaxf(l,-80.f),80.f));
    d += ww;
    fma4(a0, v, ww);
  }
  float4 acc = make_float4(a0.x+a1.x+a2.x+a3.x, a0.y+a1.y+a2.y+a3.y,
                           a0.z+a1.z+a2.z+a3.z, a0.w+a1.w+a2.w+a3.w);
  float inv = 1.f/d;
  float4 r = make_float4(
    hv.x + bb.x + (sv.x*es + acc.x)*inv,
    hv.y + bb.y + (sv.y*es + acc.y)*inv,
    hv.z + bb.z + (sv.z*es + acc.z)*inv,
    hv.w + bb.w + (sv.w*es + acc.w)*inv);
  *(float4*)&xf[(size_t)n*M + f0] = r;
  store_hl(outH, outL, (size_t)n*M + f0, r);
}

extern "C" void kernel_launch(void* const* d_in, const int* in_sizes, int n_in,
                              void* d_out, int out_size, void* d_ws, size_t ws_size,
                              hipStream_t stream) {
  const float* x0   = (const float*)d_in[0];
  const int*   ei   = (const int*)d_in[1];
  const int*   src  = ei;
  const int*   dst  = ei + NE;
  const int*   batch= (const int*)d_in[2];
  const float* gw[3]  = {(const float*)d_in[3],  (const float*)d_in[9],  (const float*)d_in[15]};
  const float* gb[3]  = {(const float*)d_in[4],  (const float*)d_in[10], (const float*)d_in[16]};
  const float* aw[3]  = {(const float*)d_in[5],  (const float*)d_in[11], (const float*)d_in[17]};
  const float* asw[3] = {(const float*)d_in[6],  (const float*)d_in[12], (const float*)d_in[18]};
  const float* adw[3] = {(const float*)d_in[7],  (const float*)d_in[13], (const float*)d_in[19]};
  const float* ab[3]  = {(const float*)d_in[8],  (const float*)d_in[14], (const float*)d_in[20]};
  const float* apw1 = (const float*)d_in[21];
  const float* apb1 = (const float*)d_in[22];
  const float* apw2 = (const float*)d_in[23];
  float* out = (float*)d_out;

  // ---- workspace carve ----
  char* p = (char*)d_ws;
  auto alloc = [&](size_t bytes) -> void* {
    void* r = (void*)p; p += (bytes + 255) & ~(size_t)255; return r;
  };
  float* f1 = (float*)alloc((size_t)NN*512*4);            // hg (mode2 out, fp32)
  float* hf = (float*)alloc((size_t)NN*512*4);            // h  (mode1 out, fp32)
  float* xf = (float*)alloc((size_t)NN*512*4);            // gat out, fp32
  unsigned short* actH0 = (unsigned short*)alloc((size_t)NN*512*2);
  unsigned short* actL0 = (unsigned short*)alloc((size_t)NN*512*2);
  unsigned short* actH1 = (unsigned short*)alloc((size_t)NN*512*2);
  unsigned short* actL1 = (unsigned short*)alloc((size_t)NN*512*2);
  unsigned short* preH  = (unsigned short*)alloc((size_t)NN*256*2);
  unsigned short* preL  = (unsigned short*)alloc((size_t)NN*256*2);
  const int wK[7]  = {36, 128, 128, 256, 256, 512, 512};
  const int wM[7]  = {128, 128, 256, 256, 512, 512, 256};
  const int wKp[7] = {64, 128, 128, 256, 256, 512, 512};
  const float* wsrc[7] = {gw[0], aw[0], gw[1], aw[1], gw[2], aw[2], apw1};
  unsigned short* wTh[7]; unsigned short* wTl[7];
  for (int i = 0; i < 7; i++){
    size_t sz = (size_t)wM[i]*wKp[i]*2;
    wTh[i] = (unsigned short*)alloc(sz);
    wTl[i] = (unsigned short*)alloc(sz);
  }
  float* dinv = (float*)alloc(NN*4);
  float* as_  = (float*)alloc(NN*NH*4);
  float* ad_  = (float*)alloc(NN*NH*4);
  float* apre = (float*)alloc(NN*4);
  int* rowptr = (int*)alloc((NN+1)*4);
  int* colidx = (int*)alloc((size_t)NE*4);
  int* cursor = (int*)alloc(NN*4);
  int* starts = (int*)alloc((NB+1)*4);
  int* perm   = (int*)alloc(NN*4);
  int* gexp   = (int*)alloc(NB*4);
  int* gdone  = (int*)alloc(NB*4);

  // ---- conv descriptor (weights only) ----
  AllConv ac;
  int convTot = 0;
  for (int i = 0; i < 7; i++){
    ac.src[i] = wsrc[i]; ac.dh[i] = wTh[i]; ac.dl[i] = wTl[i];
    ac.K[i] = wK[i]; ac.Mm[i] = wM[i]; ac.Kp[i] = wKp[i];
    ac.tot[i] = wKp[i]*wM[i];
    convTot += ac.tot[i];
  }

  // ---- CSR build: single-block scan (direct count) -> fill+conv ----
  k_scan_all<<<1, 1024, 0, stream>>>(dst, batch, rowptr, dinv, cursor, apre,
                                     starts, perm, gexp, gdone, out);
  int convBlks = (convTot + 255) / 256;
  k_fill_conv<<<CNT_BLKS + convBlks, 256, 0, stream>>>(src, dst, rowptr, cursor,
                                                       colidx, ac, convTot);

  const int dims[4] = {36, 128, 256, 512};
  const int ngrp = (NN + 15) / 16;
  int wi = 0;
  for (int i = 0; i < 3; i++){
    int Kin = (i == 0) ? 64 : dims[i];
    int M = dims[i+1], C = M/NH;
    int nchunk_in = Kin / 64;
    int nchunk = M / 64;
    int nblk = (M/GBN) * ((NN+GBM-1)/GBM);
    if (i == 0){
      k_gcn_pre0<<<ngrp, 256, 0, stream>>>(x0, dinv, rowptr, colidx, perm, preH, preL);
    } else {
      k_gcn_pre<<<nchunk_in*ngrp, 256, 0, stream>>>(xf, dinv, rowptr, colidx, perm,
                                                    preH, preL, Kin, nchunk_in);
    }
    k_gemm_bf3<<<nblk, 256, 0, stream>>>(preH, preL, wTh[wi], wTl[wi], hf, NN, wKp[wi], M,
                                         1, gb[i], actH0, actL0,
                                         nullptr, nullptr, nullptr, nullptr, C,
                                         nullptr, nullptr, nullptr, nullptr, nullptr);
    wi++;
    k_gemm_bf3<<<nblk, 256, 0, stream>>>(actH0, actL0, wTh[wi], wTl[wi], f1, NN, wKp[wi], M,
                                         2, nullptr, nullptr, nullptr,
                                         asw[i], adw[i], as_, ad_, C,
                                         nullptr, nullptr, nullptr, nullptr, nullptr);
    wi++;
    k_gat_gather<<<nchunk*ngrp, 256, 0, stream>>>(f1, hf, rowptr, colidx, perm,
                                                  as_, ad_, ab[i],
                                                  actH1, actL1, xf, M, C, nchunk);
  }

  // ---- pooling prep GEMM with fused last-block pooling ----
  {
    int nblk = (256/GBN) * ((NN+GBM-1)/GBM);
    k_gemm_bf3<<<nblk, 256, 0, stream>>>(actH1, actL1, wTh[6], wTl[6], nullptr, NN, wKp[6], 256,
                                         3, apb1, nullptr, nullptr,
                                         apw2, nullptr, apre, nullptr, 64,
                                         starts, gexp, gdone, xf, out);
  }
}

// Round 10
// 416.105 us; speedup vs baseline: 1.0662x; 1.0662x over previous
//
#include <hip/hip_runtime.h>
#include <math.h>

#define NN 10000
#define NE 160000
#define NB 128
#define NH 4
#define DOUT 512
#define NEG 0.2f
#define CNT_BLKS ((NE + 255) / 256)    // 625

typedef __attribute__((ext_vector_type(8))) short short8;
typedef __attribute__((ext_vector_type(4))) float f32x4;
typedef __attribute__((ext_vector_type(4))) unsigned short us4;

__device__ __forceinline__ float leakyf(float v){ return fmaxf(v, NEG*v); }
__device__ __forceinline__ void fma4(float4& a, const float4 v, float w){
  a.x += v.x*w; a.y += v.y*w; a.z += v.z*w; a.w += v.w*w;
}
__device__ __forceinline__ unsigned short f2bf(float f){
  unsigned int u = __float_as_uint(f);
  u += 0x7FFFu + ((u >> 16) & 1u);
  return (unsigned short)(u >> 16);
}
__device__ __forceinline__ float bf2f(unsigned short h){
  return __uint_as_float(((unsigned int)h) << 16);
}
__device__ __forceinline__ void split2(float v, unsigned short& h, unsigned short& l){
  h = f2bf(v);
  l = f2bf(v - bf2f(h));
}
__device__ __forceinline__ void store_hl(unsigned short* H, unsigned short* L,
                                         size_t base, float4 v){
  us4 h, l; unsigned short hh, ll;
  split2(v.x, hh, ll); h[0]=hh; l[0]=ll;
  split2(v.y, hh, ll); h[1]=hh; l[1]=ll;
  split2(v.z, hh, ll); h[2]=hh; l[2]=ll;
  split2(v.w, hh, ll); h[3]=hh; l[3]=ll;
  *(us4*)&H[base] = h;
  *(us4*)&L[base] = l;
}
__device__ __forceinline__ void gl_lds16(const unsigned short* g, unsigned short* l){
  __builtin_amdgcn_global_load_lds(
      (const __attribute__((address_space(1))) unsigned int*)g,
      (__attribute__((address_space(3))) unsigned int*)l, 16, 0, 0);
}

// ============ conversions descriptor (weights only; x0 handled by k_gcn_pre0) ============
struct AllConv {
  const float* src[7];
  unsigned short* dh[7];
  unsigned short* dl[7];
  int K[7], Mm[7], Kp[7], tot[7];
};

// ===== merged: edge count (blocks [0,CNT_BLKS)) + weight conversions (rest) =====
__global__ void k_count_conv(const int* __restrict__ dst, int* __restrict__ cnt,
                             AllConv a, int convTot){
  int bid = blockIdx.x;
  if (bid < CNT_BLKS){
    int e = bid*256 + threadIdx.x;
    if (e < NE) atomicAdd(&cnt[dst[e]], 1);
  } else {
    int idx = (bid - CNT_BLKS)*256 + threadIdx.x;
    if (idx >= convTot) return;
    int j = 0;
    while (idx >= a.tot[j]){ idx -= a.tot[j]; j++; }
    int Kp = a.Kp[j], K = a.K[j], M = a.Mm[j];
    int kk = idx % Kp, m = idx / Kp;
    float v = (kk < K) ? a.src[j][(size_t)kk*M + m] : 0.f;
    unsigned short h, l; split2(v, h, l);
    a.dh[j][idx] = h; a.dl[j][idx] = l;
  }
}

// ===== single-block scan (reads cnt): rowptr/dinv/cursor/apre/starts/perm +
//       pool bookkeeping (gexp/gdone, empty-graph outputs) =====
__global__ __launch_bounds__(1024) void k_scan_all(
    const int* __restrict__ cnt, const int* __restrict__ batch,
    int* __restrict__ rowptr, float* __restrict__ dinv,
    int* __restrict__ cursor, float* __restrict__ apre,
    int* __restrict__ starts, int* __restrict__ perm,
    int* __restrict__ gexp, int* __restrict__ gdone, float* __restrict__ outp){
  __shared__ int sh[NN];      // 40 KB
  __shared__ int pref[1024];
  __shared__ int hist[512];
  __shared__ int hbase[512];
  int t = threadIdx.x;
  for (int i = t; i < NN; i += 1024) sh[i] = cnt[i];
  if (t < 512) hist[t] = 0;
  if (t <= NB){
    int lo = 0, hi = NN;
    while (lo < hi){ int mid = (lo + hi) >> 1; if (batch[mid] < t) lo = mid + 1; else hi = mid; }
    starts[t] = lo;
  }
  __syncthreads();
  int base = t*10;
  int csum = 0;
#pragma unroll
  for (int k = 0; k < 10; k++){
    int i = base + k;
    if (i < NN){
      csum += sh[i];
      atomicAdd(&hist[511 - min(sh[i], 511)], 1);   // descending degree bins
    }
  }
  pref[t] = csum; __syncthreads();     // histogram + csum complete
  int horig = (t < 512) ? hist[t] : 0;
  for (int o = 1; o < 1024; o <<= 1){
    int v = (t >= o) ? pref[t - o] : 0;
    __syncthreads();
    pref[t] += v;
    __syncthreads();
  }
  for (int o = 1; o < 512; o <<= 1){
    int v = 0;
    if (t < 512 && t >= o) v = hist[t - o];
    __syncthreads();
    if (t < 512 && t >= o) hist[t] += v;
    __syncthreads();
  }
  if (t < 512) hbase[t] = hist[t] - horig;   // exclusive prefix -> scatter cursor
  __syncthreads();
  int run = pref[t] - csum;   // exclusive prefix of degrees
#pragma unroll
  for (int k = 0; k < 10; k++){
    int i = base + k;
    if (i < NN){
      int c = sh[i];
      rowptr[i] = run;
      run += c;
      dinv[i] = rsqrtf((float)c + 1.f);
      cursor[i] = 0;
      apre[i] = 0.f;
      int pos = atomicAdd(&hbase[511 - min(c, 511)], 1);
      perm[pos] = i;
    }
  }
  if (t == 1023) rowptr[NN] = pref[1023];
  __syncthreads();
  // pool bookkeeping: expected contributor count per graph (mode3 blocks: 2 col-blocks
  // per 64-row block overlapping the graph); empty graphs get identity outputs now.
  if (t < NB){
    int b0 = starts[t], e0 = starts[t+1];
    gdone[t] = 0;
    gexp[t] = (e0 > b0) ? 2*(((e0-1) >> 6) - (b0 >> 6) + 1) : 0x7fffffff;
    if (e0 == b0){
      float4* o = (float4*)(outp + (size_t)t*4*DOUT);
      float4 z = make_float4(0.f,0.f,0.f,0.f);
      float4 ni = make_float4(-INFINITY,-INFINITY,-INFINITY,-INFINITY);
      for (int q = 0; q < 128; q++){ o[q]=z; o[128+q]=z; o[256+q]=ni; o[384+q]=z; }
    }
  }
}

__global__ void k_fill(const int* __restrict__ src, const int* __restrict__ dst,
                       const int* __restrict__ rowptr, int* __restrict__ cursor,
                       int* __restrict__ colidx){
  int e = blockIdx.x*blockDim.x + threadIdx.x;
  if (e >= NE) return;
  int d = dst[e];
  int pos = atomicAdd(&cursor[d], 1);
  colidx[rowptr[d] + pos] = src[e];
}

// ===== GEMM: C[N,M] = (Ah+Al)[N,Kp] @ (Bh+Bl)^T, bf16x3, K-step 64.
//       mode==3 additionally runs fused attention-pooling via last-block pattern. =====
#define GBM 64
#define GBN 128
#define GBK 64
__global__ __launch_bounds__(256) void k_gemm_bf3(
    const unsigned short* __restrict__ Ah, const unsigned short* __restrict__ Al,
    const unsigned short* __restrict__ Bh, const unsigned short* __restrict__ Bl,
    float* __restrict__ C, int N, int Kp, int M, int mode,
    const float* __restrict__ bias, unsigned short* __restrict__ outH,
    unsigned short* __restrict__ outL,
    const float* __restrict__ a_s, const float* __restrict__ a_d,
    float* __restrict__ as_o, float* __restrict__ ad_o, int Cdim,
    const int* __restrict__ starts, const int* __restrict__ gexp,
    int* __restrict__ gdone, const float* __restrict__ xfull,
    float* __restrict__ outp){
  __shared__ unsigned short AsH[2*GBM*32], AsL[2*GBM*32];   // 8 KB each
  __shared__ unsigned short BsH[2*GBN*32], BsL[2*GBN*32];   // 16 KB each
  __shared__ float sred[2][GBM][4];
  __shared__ int winners[8];
  __shared__ int nwin;
  int gx = M / GBN;
  int gy = (N + GBM - 1) / GBM;
  const int G = 8;
  int bid = blockIdx.x;
  int full = gy / G;
  int bid_full = full * G * gx;
  int by, bx;
  if (bid < bid_full){
    int g = bid / (G*gx); int rem = bid % (G*gx);
    by = g*G + rem % G; bx = rem / G;
  } else {
    int rem = bid - bid_full; int rows = gy - full*G;
    by = full*G + rem % rows; bx = rem / rows;
  }
  int row0 = by * GBM, col0 = bx * GBN;
  int t = threadIdx.x;
  int w = t >> 6, L = t & 63;
  int lm = L & 15, lq = L >> 4;
  int wc = w * 32;

  int sr = L >> 2, sc = L & 3;
  int art = w*16 + sr;
  int ga  = (sc - ((art >> 1) & 3)) & 3;
  int agrow = min(row0 + art, N-1);
  int brt0 = w*16 + sr;
  int brt1 = (w+4)*16 + sr;
  int gb0 = (sc - ((brt0 >> 1) & 3)) & 3;
  int gb1 = (sc - ((brt1 >> 1) & 3)) & 3;
  int bgrow0 = col0 + brt0, bgrow1 = col0 + brt1;

  int rc = (lq + (lm >> 1)) & 3;
  int aoff[4], boff[2];
#pragma unroll
  for (int mi = 0; mi < 4; mi++) aoff[mi] = (mi*16 + lm)*32 + rc*8;
#pragma unroll
  for (int ni = 0; ni < 2; ni++) boff[ni] = (wc + ni*16 + lm)*32 + rc*8;

  f32x4 acc[4][2];
#pragma unroll
  for (int i = 0; i < 4; i++)
#pragma unroll
    for (int j = 0; j < 2; j++) acc[i][j] = (f32x4){0.f,0.f,0.f,0.f};

  int nk = Kp / GBK;
  for (int kt = 0; kt < nk; kt++){
    int k0 = kt * GBK;
    if (kt) __syncthreads();
#pragma unroll
    for (int h = 0; h < 2; h++){
      int kh = k0 + h*32;
      gl_lds16(&Ah[(size_t)agrow*Kp + kh + ga*8],  &AsH[h*2048 + w*512]);
      gl_lds16(&Al[(size_t)agrow*Kp + kh + ga*8],  &AsL[h*2048 + w*512]);
      gl_lds16(&Bh[(size_t)bgrow0*Kp + kh + gb0*8], &BsH[h*4096 + w*512]);
      gl_lds16(&Bh[(size_t)bgrow1*Kp + kh + gb1*8], &BsH[h*4096 + (w+4)*512]);
      gl_lds16(&Bl[(size_t)bgrow0*Kp + kh + gb0*8], &BsL[h*4096 + w*512]);
      gl_lds16(&Bl[(size_t)bgrow1*Kp + kh + gb1*8], &BsL[h*4096 + (w+4)*512]);
    }
    __syncthreads();

#pragma unroll
    for (int h = 0; h < 2; h++){
      short8 ah[4], al[4], bh[2], bl[2];
#pragma unroll
      for (int mi = 0; mi < 4; mi++){
        ah[mi] = *(const short8*)&AsH[h*2048 + aoff[mi]];
        al[mi] = *(const short8*)&AsL[h*2048 + aoff[mi]];
      }
#pragma unroll
      for (int ni = 0; ni < 2; ni++){
        bh[ni] = *(const short8*)&BsH[h*4096 + boff[ni]];
        bl[ni] = *(const short8*)&BsL[h*4096 + boff[ni]];
      }
#pragma unroll
      for (int mi = 0; mi < 4; mi++)
#pragma unroll
        for (int ni = 0; ni < 2; ni++){
          acc[mi][ni] = __builtin_amdgcn_mfma_f32_16x16x32_bf16(ah[mi], bh[ni], acc[mi][ni], 0, 0, 0);
          acc[mi][ni] = __builtin_amdgcn_mfma_f32_16x16x32_bf16(ah[mi], bl[ni], acc[mi][ni], 0, 0, 0);
          acc[mi][ni] = __builtin_amdgcn_mfma_f32_16x16x32_bf16(al[mi], bh[ni], acc[mi][ni], 0, 0, 0);
        }
    }
  }
  if (mode == 1){
    // relu + bias; store H/L (GEMM2 A-operand) AND fp32 copy (gat residual read)
#pragma unroll
    for (int mi = 0; mi < 4; mi++)
#pragma unroll
      for (int ni = 0; ni < 2; ni++){
#pragma unroll
        for (int r = 0; r < 4; r++){
          int row = row0 + mi*16 + lq*4 + r;
          int col = col0 + wc + ni*16 + lm;
          if (row < N){
            float v = fmaxf(acc[mi][ni][r] + bias[col], 0.f);
            unsigned short hh, ll; split2(v, hh, ll);
            outH[(size_t)row*M + col] = hh;
            outL[(size_t)row*M + col] = ll;
            C[(size_t)row*M + col] = v;
          }
        }
      }
  } else if (mode != 3){
#pragma unroll
    for (int mi = 0; mi < 4; mi++)
#pragma unroll
      for (int ni = 0; ni < 2; ni++){
#pragma unroll
        for (int r = 0; r < 4; r++){
          int row = row0 + mi*16 + lq*4 + r;
          int col = col0 + wc + ni*16 + lm;
          if (row < N) C[(size_t)row*M + col] = acc[mi][ni][r];
        }
      }
  }
  if (mode == 2){
    float sA0 = a_s[col0 + wc + lm], sA1 = a_s[col0 + wc + 16 + lm];
    float dA0 = a_d[col0 + wc + lm], dA1 = a_d[col0 + wc + 16 + lm];
#pragma unroll
    for (int mi = 0; mi < 4; mi++)
#pragma unroll
      for (int r = 0; r < 4; r++){
        float vs = acc[mi][0][r]*sA0 + acc[mi][1][r]*sA1;
        float vd = acc[mi][0][r]*dA0 + acc[mi][1][r]*dA1;
#pragma unroll
        for (int o = 1; o <= 8; o <<= 1){
          vs += __shfl_xor(vs, o);
          vd += __shfl_xor(vd, o);
        }
        if (lm == 0){
          int row = mi*16 + lq*4 + r;
          sred[0][row][w] = vs;
          sred[1][row][w] = vd;
        }
      }
    __syncthreads();
    if (t < GBM){
      int n = row0 + t;
      if (n < N){
        int wph = Cdim >> 5;
        int nheads = 4 / wph;
        for (int g = 0; g < nheads; g++){
          float ss = 0.f, dd = 0.f;
          for (int q = 0; q < wph; q++){
            ss += sred[0][t][g*wph + q];
            dd += sred[1][t][g*wph + q];
          }
          int hd = (col0 + g*wph*32) / Cdim;
          as_o[n*NH + hd] = ss;
          ad_o[n*NH + hd] = dd;
        }
      }
    }
  } else if (mode == 3){
    float b0 = bias[col0 + wc + lm], b1v = bias[col0 + wc + 16 + lm];
    float w0v = a_s[col0 + wc + lm], w1v = a_s[col0 + wc + 16 + lm];
#pragma unroll
    for (int mi = 0; mi < 4; mi++)
#pragma unroll
      for (int r = 0; r < 4; r++){
        float v = tanhf(acc[mi][0][r] + b0)*w0v + tanhf(acc[mi][1][r] + b1v)*w1v;
#pragma unroll
        for (int o = 1; o <= 8; o <<= 1) v += __shfl_xor(v, o);
        if (lm == 0) sred[0][mi*16 + lq*4 + r][w] = v;
      }
    __syncthreads();
    if (t < GBM){
      int n = row0 + t;
      if (n < N){
        float s = sred[0][t][0] + sred[0][t][1] + sred[0][t][2] + sred[0][t][3];
        atomicAdd(&as_o[n], s);
      }
    }
    // ---- fused attention pooling: last contributing block pools its graphs ----
    __syncthreads();
    __threadfence();
    if (t == 0){
      nwin = 0;
      int row1 = min(row0 + GBM, N);
      int glo = NB, ghi = -1;
      { int a2 = 0, b2 = NB-1;
        while (a2 <= b2){ int m2 = (a2+b2)>>1; if (starts[m2+1] > row0){ glo = m2; b2 = m2-1; } else a2 = m2+1; } }
      { int a2 = 0, b2 = NB-1;
        while (a2 <= b2){ int m2 = (a2+b2)>>1; if (starts[m2] < row1){ ghi = m2; a2 = m2+1; } else b2 = m2-1; } }
      for (int g = glo; g <= ghi && g < NB; g++){
        if (starts[g+1] > starts[g]){
          int old = atomicAdd(&gdone[g], 1);
          if (old == gexp[g]-1 && nwin < 8) winners[nwin++] = g;
        }
      }
    }
    __syncthreads();
    int nw = nwin;
    for (int wix = 0; wix < nw; wix++){
      int g = winners[wix];
      int gb = starts[g], ge = starts[g+1];
      float* red = (float*)AsH;                 // reuse staging LDS (done with it)
      float4* comb = (float4*)BsH;              // comb[3][2][128] = 12 KB < 16 KB
      float m = -INFINITY;
      for (int n = gb + t; n < ge; n += 256) m = fmaxf(m, as_o[n]);
      red[t] = m; __syncthreads();
      for (int o2 = 128; o2 > 0; o2 >>= 1){
        if (t < o2) red[t] = fmaxf(red[t], red[t + o2]);
        __syncthreads();
      }
      m = red[0]; __syncthreads();
      float s = 0.f;
      for (int n = gb + t; n < ge; n += 256) s += __expf(as_o[n] - m);
      red[t] = s; __syncthreads();
      for (int o2 = 128; o2 > 0; o2 >>= 1){
        if (t < o2) red[t] += red[t + o2];
        __syncthreads();
      }
      float inv = 1.f / (red[0] + 1e-8f);
      __syncthreads();
      int lf = t & 127, sl2 = t >> 7;           // 128 float4 feats × 2 node slices
      float4 sum = make_float4(0,0,0,0), wacc = make_float4(0,0,0,0);
      float4 mx = make_float4(-INFINITY,-INFINITY,-INFINITY,-INFINITY);
      for (int n = gb + sl2; n < ge; n += 2){
        float4 xv = *(const float4*)&xfull[(size_t)n*DOUT + lf*4];
        float pw = __expf(as_o[n] - m) * inv;
        sum.x += xv.x; sum.y += xv.y; sum.z += xv.z; sum.w += xv.w;
        mx.x = fmaxf(mx.x, xv.x); mx.y = fmaxf(mx.y, xv.y);
        mx.z = fmaxf(mx.z, xv.z); mx.w = fmaxf(mx.w, xv.w);
        fma4(wacc, xv, pw);
      }
      comb[(0*2 + sl2)*128 + lf] = wacc;
      comb[(1*2 + sl2)*128 + lf] = sum;
      comb[(2*2 + sl2)*128 + lf] = mx;
      __syncthreads();
      if (sl2 == 0){
        float4 w2 = comb[(0*2+1)*128+lf], s2 = comb[(1*2+1)*128+lf], m2 = comb[(2*2+1)*128+lf];
        wacc.x += w2.x; wacc.y += w2.y; wacc.z += w2.z; wacc.w += w2.w;
        sum.x += s2.x; sum.y += s2.y; sum.z += s2.z; sum.w += s2.w;
        mx.x = fmaxf(mx.x, m2.x); mx.y = fmaxf(mx.y, m2.y);
        mx.z = fmaxf(mx.z, m2.z); mx.w = fmaxf(mx.w, m2.w);
        float ic = 1.f / fmaxf((float)(ge - gb), 1.f);
        float4* o = (float4*)(outp + (size_t)g*4*DOUT);
        o[lf]       = wacc;
        o[128 + lf] = make_float4(sum.x*ic, sum.y*ic, sum.z*ic, sum.w*ic);
        o[256 + lf] = mx;
        o[384 + lf] = sum;
      }
      __syncthreads();
    }
  }
}

// ===== GCN pre-agg layer 0: fp32 x0 direct, 8-way, degree-sorted =====
__global__ __launch_bounds__(256) void k_gcn_pre0(
    const float* __restrict__ x0, const float* __restrict__ dinv,
    const int* __restrict__ rowptr, const int* __restrict__ colidx,
    const int* __restrict__ perm,
    unsigned short* __restrict__ outH, unsigned short* __restrict__ outL){
  int t = threadIdx.x;
  int sub = t & 15;
  int gid = blockIdx.x*16 + (t >> 4);
  if (gid >= NN) return;
  int n = perm[gid];
  int f0 = sub*4;
  bool act = f0 < 36;
  int b = rowptr[n], e = rowptr[n+1];
  float dn = dinv[n];
  float4 a0 = make_float4(0,0,0,0), a1 = make_float4(0,0,0,0);
  float4 a2 = make_float4(0,0,0,0), a3 = make_float4(0,0,0,0);
  if (act){
    float4 sv = *(const float4*)&x0[(size_t)n*36 + f0];
    int j = b;
    for (; j + 7 < e; j += 8){
      int s0 = colidx[j],   s1 = colidx[j+1], s2 = colidx[j+2], s3 = colidx[j+3];
      int s4 = colidx[j+4], s5 = colidx[j+5], s6 = colidx[j+6], s7 = colidx[j+7];
      float w0 = dinv[s0], w1 = dinv[s1], w2 = dinv[s2], w3 = dinv[s3];
      float w4 = dinv[s4], w5 = dinv[s5], w6 = dinv[s6], w7 = dinv[s7];
      float4 v0 = *(const float4*)&x0[(size_t)s0*36 + f0];
      float4 v1 = *(const float4*)&x0[(size_t)s1*36 + f0];
      float4 v2 = *(const float4*)&x0[(size_t)s2*36 + f0];
      float4 v3 = *(const float4*)&x0[(size_t)s3*36 + f0];
      float4 v4 = *(const float4*)&x0[(size_t)s4*36 + f0];
      float4 v5 = *(const float4*)&x0[(size_t)s5*36 + f0];
      float4 v6 = *(const float4*)&x0[(size_t)s6*36 + f0];
      float4 v7 = *(const float4*)&x0[(size_t)s7*36 + f0];
      fma4(a0, v0, w0*dn); fma4(a1, v1, w1*dn);
      fma4(a2, v2, w2*dn); fma4(a3, v3, w3*dn);
      fma4(a0, v4, w4*dn); fma4(a1, v5, w5*dn);
      fma4(a2, v6, w6*dn); fma4(a3, v7, w7*dn);
    }
    for (; j + 3 < e; j += 4){
      int s0 = colidx[j], s1 = colidx[j+1], s2 = colidx[j+2], s3 = colidx[j+3];
      float w0 = dinv[s0], w1 = dinv[s1], w2 = dinv[s2], w3 = dinv[s3];
      float4 v0 = *(const float4*)&x0[(size_t)s0*36 + f0];
      float4 v1 = *(const float4*)&x0[(size_t)s1*36 + f0];
      float4 v2 = *(const float4*)&x0[(size_t)s2*36 + f0];
      float4 v3 = *(const float4*)&x0[(size_t)s3*36 + f0];
      fma4(a0, v0, w0*dn); fma4(a1, v1, w1*dn);
      fma4(a2, v2, w2*dn); fma4(a3, v3, w3*dn);
    }
    for (; j < e; j++){
      int s = colidx[j];
      float4 v = *(const float4*)&x0[(size_t)s*36 + f0];
      fma4(a0, v, dinv[s]*dn);
    }
    float4 acc = make_float4(a0.x+a1.x+a2.x+a3.x, a0.y+a1.y+a2.y+a3.y,
                             a0.z+a1.z+a2.z+a3.z, a0.w+a1.w+a2.w+a3.w);
    float dn2 = dn*dn;
    acc.x += sv.x*dn2; acc.y += sv.y*dn2; acc.z += sv.z*dn2; acc.w += sv.w*dn2;
    store_hl(outH, outL, (size_t)n*64 + f0, acc);
  } else {
    store_hl(outH, outL, (size_t)n*64 + f0, make_float4(0,0,0,0));
  }
}

// ===== GCN pre-agg (layers 1..2): fp32 input (xf), 8-way, degree-sorted =====
__global__ __launch_bounds__(256) void k_gcn_pre(
    const float* __restrict__ xf, const float* __restrict__ dinv,
    const int* __restrict__ rowptr, const int* __restrict__ colidx,
    const int* __restrict__ perm,
    unsigned short* __restrict__ outH, unsigned short* __restrict__ outL,
    int Kp, int nchunk){
  int bid = blockIdx.x;
  int chunk = bid % nchunk, grp = bid / nchunk;
  int t = threadIdx.x;
  int sub = t & 15;
  int gid = grp*16 + (t >> 4);
  if (gid >= NN) return;
  int n = perm[gid];
  int f0 = chunk*64 + sub*4;
  int b = rowptr[n], e = rowptr[n+1];
  float dn = dinv[n];
  float4 sv = *(const float4*)&xf[(size_t)n*Kp + f0];
  float4 a0 = make_float4(0,0,0,0), a1 = make_float4(0,0,0,0);
  float4 a2 = make_float4(0,0,0,0), a3 = make_float4(0,0,0,0);
  int j = b;
  for (; j + 7 < e; j += 8){
    int s0 = colidx[j],   s1 = colidx[j+1], s2 = colidx[j+2], s3 = colidx[j+3];
    int s4 = colidx[j+4], s5 = colidx[j+5], s6 = colidx[j+6], s7 = colidx[j+7];
    float w0 = dinv[s0], w1 = dinv[s1], w2 = dinv[s2], w3 = dinv[s3];
    float w4 = dinv[s4], w5 = dinv[s5], w6 = dinv[s6], w7 = dinv[s7];
    float4 v0 = *(const float4*)&xf[(size_t)s0*Kp + f0];
    float4 v1 = *(const float4*)&xf[(size_t)s1*Kp + f0];
    float4 v2 = *(const float4*)&xf[(size_t)s2*Kp + f0];
    float4 v3 = *(const float4*)&xf[(size_t)s3*Kp + f0];
    float4 v4 = *(const float4*)&xf[(size_t)s4*Kp + f0];
    float4 v5 = *(const float4*)&xf[(size_t)s5*Kp + f0];
    float4 v6 = *(const float4*)&xf[(size_t)s6*Kp + f0];
    float4 v7 = *(const float4*)&xf[(size_t)s7*Kp + f0];
    fma4(a0, v0, w0*dn); fma4(a1, v1, w1*dn);
    fma4(a2, v2, w2*dn); fma4(a3, v3, w3*dn);
    fma4(a0, v4, w4*dn); fma4(a1, v5, w5*dn);
    fma4(a2, v6, w6*dn); fma4(a3, v7, w7*dn);
  }
  for (; j + 3 < e; j += 4){
    int s0 = colidx[j], s1 = colidx[j+1], s2 = colidx[j+2], s3 = colidx[j+3];
    float w0 = dinv[s0], w1 = dinv[s1], w2 = dinv[s2], w3 = dinv[s3];
    float4 v0 = *(const float4*)&xf[(size_t)s0*Kp + f0];
    float4 v1 = *(const float4*)&xf[(size_t)s1*Kp + f0];
    float4 v2 = *(const float4*)&xf[(size_t)s2*Kp + f0];
    float4 v3 = *(const float4*)&xf[(size_t)s3*Kp + f0];
    fma4(a0, v0, w0*dn); fma4(a1, v1, w1*dn);
    fma4(a2, v2, w2*dn); fma4(a3, v3, w3*dn);
  }
  for (; j < e; j++){
    int s = colidx[j];
    float4 v = *(const float4*)&xf[(size_t)s*Kp + f0];
    fma4(a0, v, dinv[s]*dn);
  }
  float4 acc = make_float4(a0.x+a1.x+a2.x+a3.x, a0.y+a1.y+a2.y+a3.y,
                           a0.z+a1.z+a2.z+a3.z, a0.w+a1.w+a2.w+a3.w);
  float dn2 = dn*dn;
  acc.x += sv.x*dn2; acc.y += sv.y*dn2; acc.z += sv.z*dn2; acc.w += sv.w*dn2;
  store_hl(outH, outL, (size_t)n*Kp + f0, acc);
}

// ===== GAT gather: fixed-shift softmax, fp32 residual, degree-sorted =====
__global__ __launch_bounds__(256) void k_gat_gather(
    const float* __restrict__ hg, const float* __restrict__ hf,
    const int* __restrict__ rowptr, const int* __restrict__ colidx,
    const int* __restrict__ perm,
    const float* __restrict__ as_, const float* __restrict__ ad_,
    const float* __restrict__ ab,
    unsigned short* __restrict__ outH, unsigned short* __restrict__ outL,
    float* __restrict__ xf,
    int M, int C, int nchunk){
  int bid = blockIdx.x;
  int chunk = bid % nchunk, grp = bid / nchunk;
  int t = threadIdx.x;
  int sub = t & 15;
  int gid = grp*16 + (t >> 4);
  if (gid >= NN) return;
  int n = perm[gid];
  int f0 = chunk*64 + sub*4;
  int hd = f0 / C;
  int b = rowptr[n], e = rowptr[n+1];
  int ai = n*NH + hd;
  float adn = ad_[ai];
  float sl = fminf(fmaxf(leakyf(as_[ai] + adn), -80.f), 80.f);
  float es = __expf(sl);
  // hoisted tail loads — latency hides under the edge loop
  float4 sv = *(const float4*)&hg[(size_t)n*M + f0];
  float4 hv = *(const float4*)&hf[(size_t)n*M + f0];
  float4 bb = *(const float4*)&ab[f0];
  float d = es;
  float4 a0 = make_float4(0,0,0,0), a1 = make_float4(0,0,0,0);
  float4 a2 = make_float4(0,0,0,0), a3 = make_float4(0,0,0,0);
  int j = b;
  for (; j + 7 < e; j += 8){
    int s0 = colidx[j],   s1 = colidx[j+1], s2 = colidx[j+2], s3 = colidx[j+3];
    int s4 = colidx[j+4], s5 = colidx[j+5], s6 = colidx[j+6], s7 = colidx[j+7];
    float l0 = leakyf(as_[s0*NH + hd] + adn), l1 = leakyf(as_[s1*NH + hd] + adn);
    float l2 = leakyf(as_[s2*NH + hd] + adn), l3 = leakyf(as_[s3*NH + hd] + adn);
    float l4 = leakyf(as_[s4*NH + hd] + adn), l5 = leakyf(as_[s5*NH + hd] + adn);
    float l6 = leakyf(as_[s6*NH + hd] + adn), l7 = leakyf(as_[s7*NH + hd] + adn);
    float4 v0 = *(const float4*)&hg[(size_t)s0*M + f0];
    float4 v1 = *(const float4*)&hg[(size_t)s1*M + f0];
    float4 v2 = *(const float4*)&hg[(size_t)s2*M + f0];
    float4 v3 = *(const float4*)&hg[(size_t)s3*M + f0];
    float4 v4 = *(const float4*)&hg[(size_t)s4*M + f0];
    float4 v5 = *(const float4*)&hg[(size_t)s5*M + f0];
    float4 v6 = *(const float4*)&hg[(size_t)s6*M + f0];
    float4 v7 = *(const float4*)&hg[(size_t)s7*M + f0];
    float w0 = __expf(fminf(fmaxf(l0,-80.f),80.f)), w1 = __expf(fminf(fmaxf(l1,-80.f),80.f));
    float w2 = __expf(fminf(fmaxf(l2,-80.f),80.f)), w3 = __expf(fminf(fmaxf(l3,-80.f),80.f));
    float w4 = __expf(fminf(fmaxf(l4,-80.f),80.f)), w5 = __expf(fminf(fmaxf(l5,-80.f),80.f));
    float w6 = __expf(fminf(fmaxf(l6,-80.f),80.f)), w7 = __expf(fminf(fmaxf(l7,-80.f),80.f));
    d += ((w0 + w1) + (w2 + w3)) + ((w4 + w5) + (w6 + w7));
    fma4(a0, v0, w0); fma4(a1, v1, w1);
    fma4(a2, v2, w2); fma4(a3, v3, w3);
    fma4(a0, v4, w4); fma4(a1, v5, w5);
    fma4(a2, v6, w6); fma4(a3, v7, w7);
  }
  for (; j < e; j++){
    int s = colidx[j];
    float l = leakyf(as_[s*NH + hd] + adn);
    float4 v = *(const float4*)&hg[(size_t)s*M + f0];
    float ww = __expf(fminf(fmaxf(l,-80.f),80.f));
    d += ww;
    fma4(a0, v, ww);
  }
  float4 acc = make_float4(a0.x+a1.x+a2.x+a3.x, a0.y+a1.y+a2.y+a3.y,
                           a0.z+a1.z+a2.z+a3.z, a0.w+a1.w+a2.w+a3.w);
  float inv = 1.f/d;
  float4 r = make_float4(
    hv.x + bb.x + (sv.x*es + acc.x)*inv,
    hv.y + bb.y + (sv.y*es + acc.y)*inv,
    hv.z + bb.z + (sv.z*es + acc.z)*inv,
    hv.w + bb.w + (sv.w*es + acc.w)*inv);
  *(float4*)&xf[(size_t)n*M + f0] = r;
  store_hl(outH, outL, (size_t)n*M + f0, r);
}

extern "C" void kernel_launch(void* const* d_in, const int* in_sizes, int n_in,
                              void* d_out, int out_size, void* d_ws, size_t ws_size,
                              hipStream_t stream) {
  const float* x0   = (const float*)d_in[0];
  const int*   ei   = (const int*)d_in[1];
  const int*   src  = ei;
  const int*   dst  = ei + NE;
  const int*   batch= (const int*)d_in[2];
  const float* gw[3]  = {(const float*)d_in[3],  (const float*)d_in[9],  (const float*)d_in[15]};
  const float* gb[3]  = {(const float*)d_in[4],  (const float*)d_in[10], (const float*)d_in[16]};
  const float* aw[3]  = {(const float*)d_in[5],  (const float*)d_in[11], (const float*)d_in[17]};
  const float* asw[3] = {(const float*)d_in[6],  (const float*)d_in[12], (const float*)d_in[18]};
  const float* adw[3] = {(const float*)d_in[7],  (const float*)d_in[13], (const float*)d_in[19]};
  const float* ab[3]  = {(const float*)d_in[8],  (const float*)d_in[14], (const float*)d_in[20]};
  const float* apw1 = (const float*)d_in[21];
  const float* apb1 = (const float*)d_in[22];
  const float* apw2 = (const float*)d_in[23];
  float* out = (float*)d_out;

  // ---- workspace carve ----
  char* p = (char*)d_ws;
  auto alloc = [&](size_t bytes) -> void* {
    void* r = (void*)p; p += (bytes + 255) & ~(size_t)255; return r;
  };
  float* f1 = (float*)alloc((size_t)NN*512*4);            // hg (mode2 out, fp32)
  float* hf = (float*)alloc((size_t)NN*512*4);            // h  (mode1 out, fp32)
  float* xf = (float*)alloc((size_t)NN*512*4);            // gat out, fp32
  unsigned short* actH0 = (unsigned short*)alloc((size_t)NN*512*2);
  unsigned short* actL0 = (unsigned short*)alloc((size_t)NN*512*2);
  unsigned short* actH1 = (unsigned short*)alloc((size_t)NN*512*2);
  unsigned short* actL1 = (unsigned short*)alloc((size_t)NN*512*2);
  unsigned short* preH  = (unsigned short*)alloc((size_t)NN*256*2);
  unsigned short* preL  = (unsigned short*)alloc((size_t)NN*256*2);
  const int wK[7]  = {36, 128, 128, 256, 256, 512, 512};
  const int wM[7]  = {128, 128, 256, 256, 512, 512, 256};
  const int wKp[7] = {64, 128, 128, 256, 256, 512, 512};
  const float* wsrc[7] = {gw[0], aw[0], gw[1], aw[1], gw[2], aw[2], apw1};
  unsigned short* wTh[7]; unsigned short* wTl[7];
  for (int i = 0; i < 7; i++){
    size_t sz = (size_t)wM[i]*wKp[i]*2;
    wTh[i] = (unsigned short*)alloc(sz);
    wTl[i] = (unsigned short*)alloc(sz);
  }
  float* dinv = (float*)alloc(NN*4);
  float* as_  = (float*)alloc(NN*NH*4);
  float* ad_  = (float*)alloc(NN*NH*4);
  float* apre = (float*)alloc(NN*4);
  int* rowptr = (int*)alloc((NN+1)*4);
  int* colidx = (int*)alloc((size_t)NE*4);
  int* cnt    = (int*)alloc(NN*4);
  int* cursor = (int*)alloc(NN*4);
  int* starts = (int*)alloc((NB+1)*4);
  int* perm   = (int*)alloc(NN*4);
  int* gexp   = (int*)alloc(NB*4);
  int* gdone  = (int*)alloc(NB*4);

  // ---- conv descriptor (weights only) ----
  AllConv ac;
  int convTot = 0;
  for (int i = 0; i < 7; i++){
    ac.src[i] = wsrc[i]; ac.dh[i] = wTh[i]; ac.dl[i] = wTl[i];
    ac.K[i] = wK[i]; ac.Mm[i] = wM[i]; ac.Kp[i] = wKp[i];
    ac.tot[i] = wKp[i]*wM[i];
    convTot += ac.tot[i];
  }

  // ---- CSR build: memset -> parallel count+conv -> scan (cnt) -> fill ----
  hipMemsetAsync(cnt, 0, NN*sizeof(int), stream);
  int convBlks = (convTot + 255) / 256;
  k_count_conv<<<CNT_BLKS + convBlks, 256, 0, stream>>>(dst, cnt, ac, convTot);
  k_scan_all<<<1, 1024, 0, stream>>>(cnt, batch, rowptr, dinv, cursor, apre,
                                     starts, perm, gexp, gdone, out);
  k_fill<<<(NE+255)/256, 256, 0, stream>>>(src, dst, rowptr, cursor, colidx);

  const int dims[4] = {36, 128, 256, 512};
  const int ngrp = (NN + 15) / 16;
  int wi = 0;
  for (int i = 0; i < 3; i++){
    int Kin = (i == 0) ? 64 : dims[i];
    int M = dims[i+1], C = M/NH;
    int nchunk_in = Kin / 64;
    int nchunk = M / 64;
    int nblk = (M/GBN) * ((NN+GBM-1)/GBM);
    if (i == 0){
      k_gcn_pre0<<<ngrp, 256, 0, stream>>>(x0, dinv, rowptr, colidx, perm, preH, preL);
    } else {
      k_gcn_pre<<<nchunk_in*ngrp, 256, 0, stream>>>(xf, dinv, rowptr, colidx, perm,
                                                    preH, preL, Kin, nchunk_in);
    }
    k_gemm_bf3<<<nblk, 256, 0, stream>>>(preH, preL, wTh[wi], wTl[wi], hf, NN, wKp[wi], M,
                                         1, gb[i], actH0, actL0,
                                         nullptr, nullptr, nullptr, nullptr, C,
                                         nullptr, nullptr, nullptr, nullptr, nullptr);
    wi++;
    k_gemm_bf3<<<nblk, 256, 0, stream>>>(actH0, actL0, wTh[wi], wTl[wi], f1, NN, wKp[wi], M,
                                         2, nullptr, nullptr, nullptr,
                                         asw[i], adw[i], as_, ad_, C,
                                         nullptr, nullptr, nullptr, nullptr, nullptr);
    wi++;
    k_gat_gather<<<nchunk*ngrp, 256, 0, stream>>>(f1, hf, rowptr, colidx, perm,
                                                  as_, ad_, ab[i],
                                                  actH1, actL1, xf, M, C, nchunk);
  }

  // ---- pooling prep GEMM with fused last-block pooling ----
  {
    int nblk = (256/GBN) * ((NN+GBM-1)/GBM);
    k_gemm_bf3<<<nblk, 256, 0, stream>>>(actH1, actL1, wTh[6], wTl[6], nullptr, NN, wKp[6], 256,
                                         3, apb1, nullptr, nullptr,
                                         apw2, nullptr, apre, nullptr, 64,
                                         starts, gexp, gdone, xf, out);
  }
}

// Round 11
// 379.061 us; speedup vs baseline: 1.1704x; 1.0977x over previous
//
#include <hip/hip_runtime.h>
#include <math.h>

#define NN 10000
#define NE 160000
#define NB 128
#define NH 4
#define DOUT 512
#define NEG 0.2f
#define CNT_BLKS ((NE + 255) / 256)    // 625

typedef __attribute__((ext_vector_type(8))) short short8;
typedef __attribute__((ext_vector_type(4))) float f32x4;
typedef __attribute__((ext_vector_type(4))) unsigned short us4;

__device__ __forceinline__ float leakyf(float v){ return fmaxf(v, NEG*v); }
__device__ __forceinline__ void fma4(float4& a, const float4 v, float w){
  a.x += v.x*w; a.y += v.y*w; a.z += v.z*w; a.w += v.w*w;
}
__device__ __forceinline__ unsigned short f2bf(float f){
  unsigned int u = __float_as_uint(f);
  u += 0x7FFFu + ((u >> 16) & 1u);
  return (unsigned short)(u >> 16);
}
__device__ __forceinline__ float bf2f(unsigned short h){
  return __uint_as_float(((unsigned int)h) << 16);
}
__device__ __forceinline__ void split2(float v, unsigned short& h, unsigned short& l){
  h = f2bf(v);
  l = f2bf(v - bf2f(h));
}
__device__ __forceinline__ void store_hl(unsigned short* H, unsigned short* L,
                                         size_t base, float4 v){
  us4 h, l; unsigned short hh, ll;
  split2(v.x, hh, ll); h[0]=hh; l[0]=ll;
  split2(v.y, hh, ll); h[1]=hh; l[1]=ll;
  split2(v.z, hh, ll); h[2]=hh; l[2]=ll;
  split2(v.w, hh, ll); h[3]=hh; l[3]=ll;
  *(us4*)&H[base] = h;
  *(us4*)&L[base] = l;
}
__device__ __forceinline__ void gl_lds16(const unsigned short* g, unsigned short* l){
  __builtin_amdgcn_global_load_lds(
      (const __attribute__((address_space(1))) unsigned int*)g,
      (__attribute__((address_space(3))) unsigned int*)l, 16, 0, 0);
}

// ============ conversions descriptor (weights only; x0 handled by k_gcn_pre0) ============
struct AllConv {
  const float* src[7];
  unsigned short* dh[7];
  unsigned short* dl[7];
  int K[7], Mm[7], Kp[7], tot[7];
};

// ===== merged: edge count (blocks [0,CNT_BLKS)) + weight conversions (rest) =====
__global__ void k_count_conv(const int* __restrict__ dst, int* __restrict__ cnt,
                             AllConv a, int convTot){
  int bid = blockIdx.x;
  if (bid < CNT_BLKS){
    int e = bid*256 + threadIdx.x;
    if (e < NE) atomicAdd(&cnt[dst[e]], 1);
  } else {
    int idx = (bid - CNT_BLKS)*256 + threadIdx.x;
    if (idx >= convTot) return;
    int j = 0;
    while (idx >= a.tot[j]){ idx -= a.tot[j]; j++; }
    int Kp = a.Kp[j], K = a.K[j], M = a.Mm[j];
    int kk = idx % Kp, m = idx / Kp;
    float v = (kk < K) ? a.src[j][(size_t)kk*M + m] : 0.f;
    unsigned short h, l; split2(v, h, l);
    a.dh[j][idx] = h; a.dl[j][idx] = l;
  }
}

// ===== single-block scan: rowptr/dinv/cursor/apre/starts + degree-sorted perm =====
__global__ __launch_bounds__(1024) void k_scan_all(
    const int* __restrict__ cnt, const int* __restrict__ batch,
    int* __restrict__ rowptr, float* __restrict__ dinv,
    int* __restrict__ cursor, float* __restrict__ apre,
    int* __restrict__ starts, int* __restrict__ perm){
  __shared__ int sh[NN];      // 40 KB
  __shared__ int pref[1024];
  __shared__ int hist[512];
  __shared__ int hbase[512];
  int t = threadIdx.x;
  for (int i = t; i < NN; i += 1024) sh[i] = cnt[i];
  if (t < 512) hist[t] = 0;
  if (t <= NB){
    int lo = 0, hi = NN;
    while (lo < hi){ int mid = (lo + hi) >> 1; if (batch[mid] < t) lo = mid + 1; else hi = mid; }
    starts[t] = lo;
  }
  __syncthreads();
  int base = t*10;
  int csum = 0;
#pragma unroll
  for (int k = 0; k < 10; k++){
    int i = base + k;
    if (i < NN){
      csum += sh[i];
      atomicAdd(&hist[511 - min(sh[i], 511)], 1);   // descending degree bins
    }
  }
  pref[t] = csum; __syncthreads();     // histogram + csum complete
  int horig = (t < 512) ? hist[t] : 0;
  for (int o = 1; o < 1024; o <<= 1){
    int v = (t >= o) ? pref[t - o] : 0;
    __syncthreads();
    pref[t] += v;
    __syncthreads();
  }
  for (int o = 1; o < 512; o <<= 1){
    int v = 0;
    if (t < 512 && t >= o) v = hist[t - o];
    __syncthreads();
    if (t < 512 && t >= o) hist[t] += v;
    __syncthreads();
  }
  if (t < 512) hbase[t] = hist[t] - horig;   // exclusive prefix -> scatter cursor
  __syncthreads();
  int run = pref[t] - csum;   // exclusive prefix of degrees
#pragma unroll
  for (int k = 0; k < 10; k++){
    int i = base + k;
    if (i < NN){
      int c = sh[i];
      rowptr[i] = run;
      run += c;
      dinv[i] = rsqrtf((float)c + 1.f);
      cursor[i] = 0;
      apre[i] = 0.f;
      int pos = atomicAdd(&hbase[511 - min(c, 511)], 1);
      perm[pos] = i;
    }
  }
  if (t == 1023) rowptr[NN] = pref[1023];
}

__global__ void k_fill(const int* __restrict__ src, const int* __restrict__ dst,
                       const int* __restrict__ rowptr, int* __restrict__ cursor,
                       int* __restrict__ colidx){
  int e = blockIdx.x*blockDim.x + threadIdx.x;
  if (e >= NE) return;
  int d = dst[e];
  int pos = atomicAdd(&cursor[d], 1);
  colidx[rowptr[d] + pos] = src[e];
}

// ===== GEMM: C[N,M] = (Ah+Al)[N,Kp] @ (Bh+Bl)^T, bf16x3, K-step 64 =====
#define GBM 64
#define GBN 128
#define GBK 64
__global__ __launch_bounds__(256) void k_gemm_bf3(
    const unsigned short* __restrict__ Ah, const unsigned short* __restrict__ Al,
    const unsigned short* __restrict__ Bh, const unsigned short* __restrict__ Bl,
    float* __restrict__ C, int N, int Kp, int M, int mode,
    const float* __restrict__ bias, unsigned short* __restrict__ outH,
    unsigned short* __restrict__ outL,
    const float* __restrict__ a_s, const float* __restrict__ a_d,
    float* __restrict__ as_o, float* __restrict__ ad_o, int Cdim){
  __shared__ unsigned short AsH[2*GBM*32], AsL[2*GBM*32];
  __shared__ unsigned short BsH[2*GBN*32], BsL[2*GBN*32];
  __shared__ float sred[2][GBM][4];
  int gx = M / GBN;
  int gy = (N + GBM - 1) / GBM;
  const int G = 8;
  int bid = blockIdx.x;
  int full = gy / G;
  int bid_full = full * G * gx;
  int by, bx;
  if (bid < bid_full){
    int g = bid / (G*gx); int rem = bid % (G*gx);
    by = g*G + rem % G; bx = rem / G;
  } else {
    int rem = bid - bid_full; int rows = gy - full*G;
    by = full*G + rem % rows; bx = rem / rows;
  }
  int row0 = by * GBM, col0 = bx * GBN;
  int t = threadIdx.x;
  int w = t >> 6, L = t & 63;
  int lm = L & 15, lq = L >> 4;
  int wc = w * 32;

  int sr = L >> 2, sc = L & 3;
  int art = w*16 + sr;
  int ga  = (sc - ((art >> 1) & 3)) & 3;
  int agrow = min(row0 + art, N-1);
  int brt0 = w*16 + sr;
  int brt1 = (w+4)*16 + sr;
  int gb0 = (sc - ((brt0 >> 1) & 3)) & 3;
  int gb1 = (sc - ((brt1 >> 1) & 3)) & 3;
  int bgrow0 = col0 + brt0, bgrow1 = col0 + brt1;

  int rc = (lq + (lm >> 1)) & 3;
  int aoff[4], boff[2];
#pragma unroll
  for (int mi = 0; mi < 4; mi++) aoff[mi] = (mi*16 + lm)*32 + rc*8;
#pragma unroll
  for (int ni = 0; ni < 2; ni++) boff[ni] = (wc + ni*16 + lm)*32 + rc*8;

  f32x4 acc[4][2];
#pragma unroll
  for (int i = 0; i < 4; i++)
#pragma unroll
    for (int j = 0; j < 2; j++) acc[i][j] = (f32x4){0.f,0.f,0.f,0.f};

  int nk = Kp / GBK;
  for (int kt = 0; kt < nk; kt++){
    int k0 = kt * GBK;
    if (kt) __syncthreads();
#pragma unroll
    for (int h = 0; h < 2; h++){
      int kh = k0 + h*32;
      gl_lds16(&Ah[(size_t)agrow*Kp + kh + ga*8],  &AsH[h*2048 + w*512]);
      gl_lds16(&Al[(size_t)agrow*Kp + kh + ga*8],  &AsL[h*2048 + w*512]);
      gl_lds16(&Bh[(size_t)bgrow0*Kp + kh + gb0*8], &BsH[h*4096 + w*512]);
      gl_lds16(&Bh[(size_t)bgrow1*Kp + kh + gb1*8], &BsH[h*4096 + (w+4)*512]);
      gl_lds16(&Bl[(size_t)bgrow0*Kp + kh + gb0*8], &BsL[h*4096 + w*512]);
      gl_lds16(&Bl[(size_t)bgrow1*Kp + kh + gb1*8], &BsL[h*4096 + (w+4)*512]);
    }
    __syncthreads();

#pragma unroll
    for (int h = 0; h < 2; h++){
      short8 ah[4], al[4], bh[2], bl[2];
#pragma unroll
      for (int mi = 0; mi < 4; mi++){
        ah[mi] = *(const short8*)&AsH[h*2048 + aoff[mi]];
        al[mi] = *(const short8*)&AsL[h*2048 + aoff[mi]];
      }
#pragma unroll
      for (int ni = 0; ni < 2; ni++){
        bh[ni] = *(const short8*)&BsH[h*4096 + boff[ni]];
        bl[ni] = *(const short8*)&BsL[h*4096 + boff[ni]];
      }
#pragma unroll
      for (int mi = 0; mi < 4; mi++)
#pragma unroll
        for (int ni = 0; ni < 2; ni++){
          acc[mi][ni] = __builtin_amdgcn_mfma_f32_16x16x32_bf16(ah[mi], bh[ni], acc[mi][ni], 0, 0, 0);
          acc[mi][ni] = __builtin_amdgcn_mfma_f32_16x16x32_bf16(ah[mi], bl[ni], acc[mi][ni], 0, 0, 0);
          acc[mi][ni] = __builtin_amdgcn_mfma_f32_16x16x32_bf16(al[mi], bh[ni], acc[mi][ni], 0, 0, 0);
        }
    }
  }
  if (mode == 1){
    // relu + bias; store H/L (GEMM2 A-operand) AND fp32 copy (gat residual read)
#pragma unroll
    for (int mi = 0; mi < 4; mi++)
#pragma unroll
      for (int ni = 0; ni < 2; ni++){
#pragma unroll
        for (int r = 0; r < 4; r++){
          int row = row0 + mi*16 + lq*4 + r;
          int col = col0 + wc + ni*16 + lm;
          if (row < N){
            float v = fmaxf(acc[mi][ni][r] + bias[col], 0.f);
            unsigned short hh, ll; split2(v, hh, ll);
            outH[(size_t)row*M + col] = hh;
            outL[(size_t)row*M + col] = ll;
            C[(size_t)row*M + col] = v;
          }
        }
      }
  } else if (mode != 3){
#pragma unroll
    for (int mi = 0; mi < 4; mi++)
#pragma unroll
      for (int ni = 0; ni < 2; ni++){
#pragma unroll
        for (int r = 0; r < 4; r++){
          int row = row0 + mi*16 + lq*4 + r;
          int col = col0 + wc + ni*16 + lm;
          if (row < N) C[(size_t)row*M + col] = acc[mi][ni][r];
        }
      }
  }
  if (mode == 2){
    float sA0 = a_s[col0 + wc + lm], sA1 = a_s[col0 + wc + 16 + lm];
    float dA0 = a_d[col0 + wc + lm], dA1 = a_d[col0 + wc + 16 + lm];
#pragma unroll
    for (int mi = 0; mi < 4; mi++)
#pragma unroll
      for (int r = 0; r < 4; r++){
        float vs = acc[mi][0][r]*sA0 + acc[mi][1][r]*sA1;
        float vd = acc[mi][0][r]*dA0 + acc[mi][1][r]*dA1;
#pragma unroll
        for (int o = 1; o <= 8; o <<= 1){
          vs += __shfl_xor(vs, o);
          vd += __shfl_xor(vd, o);
        }
        if (lm == 0){
          int row = mi*16 + lq*4 + r;
          sred[0][row][w] = vs;
          sred[1][row][w] = vd;
        }
      }
    __syncthreads();
    if (t < GBM){
      int n = row0 + t;
      if (n < N){
        int wph = Cdim >> 5;
        int nheads = 4 / wph;
        for (int g = 0; g < nheads; g++){
          float ss = 0.f, dd = 0.f;
          for (int q = 0; q < wph; q++){
            ss += sred[0][t][g*wph + q];
            dd += sred[1][t][g*wph + q];
          }
          int hd = (col0 + g*wph*32) / Cdim;
          as_o[n*NH + hd] = ss;
          ad_o[n*NH + hd] = dd;
        }
      }
    }
  } else if (mode == 3){
    float b0 = bias[col0 + wc + lm], b1v = bias[col0 + wc + 16 + lm];
    float w0v = a_s[col0 + wc + lm], w1v = a_s[col0 + wc + 16 + lm];
#pragma unroll
    for (int mi = 0; mi < 4; mi++)
#pragma unroll
      for (int r = 0; r < 4; r++){
        float v = tanhf(acc[mi][0][r] + b0)*w0v + tanhf(acc[mi][1][r] + b1v)*w1v;
#pragma unroll
        for (int o = 1; o <= 8; o <<= 1) v += __shfl_xor(v, o);
        if (lm == 0) sred[0][mi*16 + lq*4 + r][w] = v;
      }
    __syncthreads();
    if (t < GBM){
      int n = row0 + t;
      if (n < N){
        float s = sred[0][t][0] + sred[0][t][1] + sred[0][t][2] + sred[0][t][3];
        atomicAdd(&as_o[n], s);
      }
    }
  }
}

// ===== GCN pre-agg layer 0: fp32 x0 direct, 8-way, degree-sorted =====
__global__ __launch_bounds__(256) void k_gcn_pre0(
    const float* __restrict__ x0, const float* __restrict__ dinv,
    const int* __restrict__ rowptr, const int* __restrict__ colidx,
    const int* __restrict__ perm,
    unsigned short* __restrict__ outH, unsigned short* __restrict__ outL){
  int t = threadIdx.x;
  int sub = t & 15;
  int gid = blockIdx.x*16 + (t >> 4);
  if (gid >= NN) return;
  int n = perm[gid];
  int f0 = sub*4;
  bool act = f0 < 36;
  int b = rowptr[n], e = rowptr[n+1];
  float dn = dinv[n];
  float4 a0 = make_float4(0,0,0,0), a1 = make_float4(0,0,0,0);
  float4 a2 = make_float4(0,0,0,0), a3 = make_float4(0,0,0,0);
  if (act){
    float4 sv = *(const float4*)&x0[(size_t)n*36 + f0];
    int j = b;
    for (; j + 7 < e; j += 8){
      int s0 = colidx[j],   s1 = colidx[j+1], s2 = colidx[j+2], s3 = colidx[j+3];
      int s4 = colidx[j+4], s5 = colidx[j+5], s6 = colidx[j+6], s7 = colidx[j+7];
      float w0 = dinv[s0], w1 = dinv[s1], w2 = dinv[s2], w3 = dinv[s3];
      float w4 = dinv[s4], w5 = dinv[s5], w6 = dinv[s6], w7 = dinv[s7];
      float4 v0 = *(const float4*)&x0[(size_t)s0*36 + f0];
      float4 v1 = *(const float4*)&x0[(size_t)s1*36 + f0];
      float4 v2 = *(const float4*)&x0[(size_t)s2*36 + f0];
      float4 v3 = *(const float4*)&x0[(size_t)s3*36 + f0];
      float4 v4 = *(const float4*)&x0[(size_t)s4*36 + f0];
      float4 v5 = *(const float4*)&x0[(size_t)s5*36 + f0];
      float4 v6 = *(const float4*)&x0[(size_t)s6*36 + f0];
      float4 v7 = *(const float4*)&x0[(size_t)s7*36 + f0];
      fma4(a0, v0, w0*dn); fma4(a1, v1, w1*dn);
      fma4(a2, v2, w2*dn); fma4(a3, v3, w3*dn);
      fma4(a0, v4, w4*dn); fma4(a1, v5, w5*dn);
      fma4(a2, v6, w6*dn); fma4(a3, v7, w7*dn);
    }
    for (; j + 3 < e; j += 4){
      int s0 = colidx[j], s1 = colidx[j+1], s2 = colidx[j+2], s3 = colidx[j+3];
      float w0 = dinv[s0], w1 = dinv[s1], w2 = dinv[s2], w3 = dinv[s3];
      float4 v0 = *(const float4*)&x0[(size_t)s0*36 + f0];
      float4 v1 = *(const float4*)&x0[(size_t)s1*36 + f0];
      float4 v2 = *(const float4*)&x0[(size_t)s2*36 + f0];
      float4 v3 = *(const float4*)&x0[(size_t)s3*36 + f0];
      fma4(a0, v0, w0*dn); fma4(a1, v1, w1*dn);
      fma4(a2, v2, w2*dn); fma4(a3, v3, w3*dn);
    }
    for (; j < e; j++){
      int s = colidx[j];
      float4 v = *(const float4*)&x0[(size_t)s*36 + f0];
      fma4(a0, v, dinv[s]*dn);
    }
    float4 acc = make_float4(a0.x+a1.x+a2.x+a3.x, a0.y+a1.y+a2.y+a3.y,
                             a0.z+a1.z+a2.z+a3.z, a0.w+a1.w+a2.w+a3.w);
    float dn2 = dn*dn;
    acc.x += sv.x*dn2; acc.y += sv.y*dn2; acc.z += sv.z*dn2; acc.w += sv.w*dn2;
    store_hl(outH, outL, (size_t)n*64 + f0, acc);
  } else {
    store_hl(outH, outL, (size_t)n*64 + f0, make_float4(0,0,0,0));
  }
}

// ===== GCN pre-agg (layers 1..2): fp32 input (xf), 8-way, degree-sorted =====
__global__ __launch_bounds__(256) void k_gcn_pre(
    const float* __restrict__ xf, const float* __restrict__ dinv,
    const int* __restrict__ rowptr, const int* __restrict__ colidx,
    const int* __restrict__ perm,
    unsigned short* __restrict__ outH, unsigned short* __restrict__ outL,
    int Kp, int nchunk){
  int bid = blockIdx.x;
  int chunk = bid % nchunk, grp = bid / nchunk;
  int t = threadIdx.x;
  int sub = t & 15;
  int gid = grp*16 + (t >> 4);
  if (gid >= NN) return;
  int n = perm[gid];
  int f0 = chunk*64 + sub*4;
  int b = rowptr[n], e = rowptr[n+1];
  float dn = dinv[n];
  float4 sv = *(const float4*)&xf[(size_t)n*Kp + f0];
  float4 a0 = make_float4(0,0,0,0), a1 = make_float4(0,0,0,0);
  float4 a2 = make_float4(0,0,0,0), a3 = make_float4(0,0,0,0);
  int j = b;
  for (; j + 7 < e; j += 8){
    int s0 = colidx[j],   s1 = colidx[j+1], s2 = colidx[j+2], s3 = colidx[j+3];
    int s4 = colidx[j+4], s5 = colidx[j+5], s6 = colidx[j+6], s7 = colidx[j+7];
    float w0 = dinv[s0], w1 = dinv[s1], w2 = dinv[s2], w3 = dinv[s3];
    float w4 = dinv[s4], w5 = dinv[s5], w6 = dinv[s6], w7 = dinv[s7];
    float4 v0 = *(const float4*)&xf[(size_t)s0*Kp + f0];
    float4 v1 = *(const float4*)&xf[(size_t)s1*Kp + f0];
    float4 v2 = *(const float4*)&xf[(size_t)s2*Kp + f0];
    float4 v3 = *(const float4*)&xf[(size_t)s3*Kp + f0];
    float4 v4 = *(const float4*)&xf[(size_t)s4*Kp + f0];
    float4 v5 = *(const float4*)&xf[(size_t)s5*Kp + f0];
    float4 v6 = *(const float4*)&xf[(size_t)s6*Kp + f0];
    float4 v7 = *(const float4*)&xf[(size_t)s7*Kp + f0];
    fma4(a0, v0, w0*dn); fma4(a1, v1, w1*dn);
    fma4(a2, v2, w2*dn); fma4(a3, v3, w3*dn);
    fma4(a0, v4, w4*dn); fma4(a1, v5, w5*dn);
    fma4(a2, v6, w6*dn); fma4(a3, v7, w7*dn);
  }
  for (; j + 3 < e; j += 4){
    int s0 = colidx[j], s1 = colidx[j+1], s2 = colidx[j+2], s3 = colidx[j+3];
    float w0 = dinv[s0], w1 = dinv[s1], w2 = dinv[s2], w3 = dinv[s3];
    float4 v0 = *(const float4*)&xf[(size_t)s0*Kp + f0];
    float4 v1 = *(const float4*)&xf[(size_t)s1*Kp + f0];
    float4 v2 = *(const float4*)&xf[(size_t)s2*Kp + f0];
    float4 v3 = *(const float4*)&xf[(size_t)s3*Kp + f0];
    fma4(a0, v0, w0*dn); fma4(a1, v1, w1*dn);
    fma4(a2, v2, w2*dn); fma4(a3, v3, w3*dn);
  }
  for (; j < e; j++){
    int s = colidx[j];
    float4 v = *(const float4*)&xf[(size_t)s*Kp + f0];
    fma4(a0, v, dinv[s]*dn);
  }
  float4 acc = make_float4(a0.x+a1.x+a2.x+a3.x, a0.y+a1.y+a2.y+a3.y,
                           a0.z+a1.z+a2.z+a3.z, a0.w+a1.w+a2.w+a3.w);
  float dn2 = dn*dn;
  acc.x += sv.x*dn2; acc.y += sv.y*dn2; acc.z += sv.z*dn2; acc.w += sv.w*dn2;
  store_hl(outH, outL, (size_t)n*Kp + f0, acc);
}

// ===== GAT gather: fixed-shift softmax, fp32 residual, degree-sorted.
//       H/L store only when writeHL (layer 3 — only consumer is mode-3 GEMM) =====
__global__ __launch_bounds__(256) void k_gat_gather(
    const float* __restrict__ hg, const float* __restrict__ hf,
    const int* __restrict__ rowptr, const int* __restrict__ colidx,
    const int* __restrict__ perm,
    const float* __restrict__ as_, const float* __restrict__ ad_,
    const float* __restrict__ ab,
    unsigned short* __restrict__ outH, unsigned short* __restrict__ outL,
    float* __restrict__ xf,
    int M, int C, int nchunk, int writeHL){
  int bid = blockIdx.x;
  int chunk = bid % nchunk, grp = bid / nchunk;
  int t = threadIdx.x;
  int sub = t & 15;
  int gid = grp*16 + (t >> 4);
  if (gid >= NN) return;
  int n = perm[gid];
  int f0 = chunk*64 + sub*4;
  int hd = f0 / C;
  int b = rowptr[n], e = rowptr[n+1];
  int ai = n*NH + hd;
  float adn = ad_[ai];
  float sl = fminf(fmaxf(leakyf(as_[ai] + adn), -80.f), 80.f);
  float es = __expf(sl);
  // hoisted tail loads — latency hides under the edge loop
  float4 sv = *(const float4*)&hg[(size_t)n*M + f0];
  float4 hv = *(const float4*)&hf[(size_t)n*M + f0];
  float4 bb = *(const float4*)&ab[f0];
  float d = es;
  float4 a0 = make_float4(0,0,0,0), a1 = make_float4(0,0,0,0);
  float4 a2 = make_float4(0,0,0,0), a3 = make_float4(0,0,0,0);
  int j = b;
  for (; j + 7 < e; j += 8){
    int s0 = colidx[j],   s1 = colidx[j+1], s2 = colidx[j+2], s3 = colidx[j+3];
    int s4 = colidx[j+4], s5 = colidx[j+5], s6 = colidx[j+6], s7 = colidx[j+7];
    float l0 = leakyf(as_[s0*NH + hd] + adn), l1 = leakyf(as_[s1*NH + hd] + adn);
    float l2 = leakyf(as_[s2*NH + hd] + adn), l3 = leakyf(as_[s3*NH + hd] + adn);
    float l4 = leakyf(as_[s4*NH + hd] + adn), l5 = leakyf(as_[s5*NH + hd] + adn);
    float l6 = leakyf(as_[s6*NH + hd] + adn), l7 = leakyf(as_[s7*NH + hd] + adn);
    float4 v0 = *(const float4*)&hg[(size_t)s0*M + f0];
    float4 v1 = *(const float4*)&hg[(size_t)s1*M + f0];
    float4 v2 = *(const float4*)&hg[(size_t)s2*M + f0];
    float4 v3 = *(const float4*)&hg[(size_t)s3*M + f0];
    float4 v4 = *(const float4*)&hg[(size_t)s4*M + f0];
    float4 v5 = *(const float4*)&hg[(size_t)s5*M + f0];
    float4 v6 = *(const float4*)&hg[(size_t)s6*M + f0];
    float4 v7 = *(const float4*)&hg[(size_t)s7*M + f0];
    float w0 = __expf(fminf(fmaxf(l0,-80.f),80.f)), w1 = __expf(fminf(fmaxf(l1,-80.f),80.f));
    float w2 = __expf(fminf(fmaxf(l2,-80.f),80.f)), w3 = __expf(fminf(fmaxf(l3,-80.f),80.f));
    float w4 = __expf(fminf(fmaxf(l4,-80.f),80.f)), w5 = __expf(fminf(fmaxf(l5,-80.f),80.f));
    float w6 = __expf(fminf(fmaxf(l6,-80.f),80.f)), w7 = __expf(fminf(fmaxf(l7,-80.f),80.f));
    d += ((w0 + w1) + (w2 + w3)) + ((w4 + w5) + (w6 + w7));
    fma4(a0, v0, w0); fma4(a1, v1, w1);
    fma4(a2, v2, w2); fma4(a3, v3, w3);
    fma4(a0, v4, w4); fma4(a1, v5, w5);
    fma4(a2, v6, w6); fma4(a3, v7, w7);
  }
  for (; j < e; j++){
    int s = colidx[j];
    float l = leakyf(as_[s*NH + hd] + adn);
    float4 v = *(const float4*)&hg[(size_t)s*M + f0];
    float ww = __expf(fminf(fmaxf(l,-80.f),80.f));
    d += ww;
    fma4(a0, v, ww);
  }
  float4 acc = make_float4(a0.x+a1.x+a2.x+a3.x, a0.y+a1.y+a2.y+a3.y,
                           a0.z+a1.z+a2.z+a3.z, a0.w+a1.w+a2.w+a3.w);
  float inv = 1.f/d;
  float4 r = make_float4(
    hv.x + bb.x + (sv.x*es + acc.x)*inv,
    hv.y + bb.y + (sv.y*es + acc.y)*inv,
    hv.z + bb.z + (sv.z*es + acc.z)*inv,
    hv.w + bb.w + (sv.w*es + acc.w)*inv);
  *(float4*)&xf[(size_t)n*M + f0] = r;
  if (writeHL) store_hl(outH, outL, (size_t)n*M + f0, r);
}

// ====== attention pooling: 2 blocks/graph (feature halves), 8-way node slice ======
__global__ __launch_bounds__(512) void k_pool(
    const float* __restrict__ xf,
    const float* __restrict__ apre, const int* __restrict__ starts,
    float* __restrict__ out){
  __shared__ float red[512];
  __shared__ float4 comb[3][8][64];   // 24 KB
  int g = blockIdx.x >> 1, half = blockIdx.x & 1;
  int t = threadIdx.x;
  int b = starts[g], e = starts[g+1];
  float m = -INFINITY;
  for (int n = b + t; n < e; n += 512) m = fmaxf(m, apre[n]);
  red[t] = m; __syncthreads();
  for (int o = 256; o > 0; o >>= 1){
    if (t < o) red[t] = fmaxf(red[t], red[t + o]);
    __syncthreads();
  }
  m = red[0]; __syncthreads();
  float s = 0.f;
  for (int n = b + t; n < e; n += 512) s += __expf(apre[n] - m);
  red[t] = s; __syncthreads();
  for (int o = 256; o > 0; o >>= 1){
    if (t < o) red[t] += red[t + o];
    __syncthreads();
  }
  float inv = 1.f / (red[0] + 1e-8f);
  int lf = t & 63, sl = t >> 6;          // 64 float4 feats × 8 node-slices
  int fo = half*64 + lf;                 // float4 index in [0,128)
  float4 sum = make_float4(0,0,0,0), wacc = make_float4(0,0,0,0);
  float4 mx = make_float4(-INFINITY,-INFINITY,-INFINITY,-INFINITY);
  for (int n = b + sl; n < e; n += 8){
    float4 xv = *(const float4*)&xf[(size_t)n*DOUT + fo*4];
    float p = __expf(apre[n] - m) * inv;
    sum.x += xv.x; sum.y += xv.y; sum.z += xv.z; sum.w += xv.w;
    mx.x = fmaxf(mx.x, xv.x); mx.y = fmaxf(mx.y, xv.y);
    mx.z = fmaxf(mx.z, xv.z); mx.w = fmaxf(mx.w, xv.w);
    fma4(wacc, xv, p);
  }
  comb[0][sl][lf] = wacc; comb[1][sl][lf] = sum; comb[2][sl][lf] = mx;
  __syncthreads();
  if (sl == 0){
#pragma unroll
    for (int q = 1; q < 8; q++){
      float4 w2 = comb[0][q][lf], s2 = comb[1][q][lf], m2 = comb[2][q][lf];
      wacc.x += w2.x; wacc.y += w2.y; wacc.z += w2.z; wacc.w += w2.w;
      sum.x += s2.x; sum.y += s2.y; sum.z += s2.z; sum.w += s2.w;
      mx.x = fmaxf(mx.x, m2.x); mx.y = fmaxf(mx.y, m2.y);
      mx.z = fmaxf(mx.z, m2.z); mx.w = fmaxf(mx.w, m2.w);
    }
    float ic = 1.f / fmaxf((float)(e - b), 1.f);
    float4* o = (float4*)(out + (size_t)g*4*DOUT);
    o[fo]       = wacc;
    o[128 + fo] = make_float4(sum.x*ic, sum.y*ic, sum.z*ic, sum.w*ic);
    o[256 + fo] = mx;
    o[384 + fo] = sum;
  }
}

extern "C" void kernel_launch(void* const* d_in, const int* in_sizes, int n_in,
                              void* d_out, int out_size, void* d_ws, size_t ws_size,
                              hipStream_t stream) {
  const float* x0   = (const float*)d_in[0];
  const int*   ei   = (const int*)d_in[1];
  const int*   src  = ei;
  const int*   dst  = ei + NE;
  const int*   batch= (const int*)d_in[2];
  const float* gw[3]  = {(const float*)d_in[3],  (const float*)d_in[9],  (const float*)d_in[15]};
  const float* gb[3]  = {(const float*)d_in[4],  (const float*)d_in[10], (const float*)d_in[16]};
  const float* aw[3]  = {(const float*)d_in[5],  (const float*)d_in[11], (const float*)d_in[17]};
  const float* asw[3] = {(const float*)d_in[6],  (const float*)d_in[12], (const float*)d_in[18]};
  const float* adw[3] = {(const float*)d_in[7],  (const float*)d_in[13], (const float*)d_in[19]};
  const float* ab[3]  = {(const float*)d_in[8],  (const float*)d_in[14], (const float*)d_in[20]};
  const float* apw1 = (const float*)d_in[21];
  const float* apb1 = (const float*)d_in[22];
  const float* apw2 = (const float*)d_in[23];
  float* out = (float*)d_out;

  // ---- workspace carve ----
  char* p = (char*)d_ws;
  auto alloc = [&](size_t bytes) -> void* {
    void* r = (void*)p; p += (bytes + 255) & ~(size_t)255; return r;
  };
  float* f1 = (float*)alloc((size_t)NN*512*4);            // hg (mode2 out, fp32)
  float* hf = (float*)alloc((size_t)NN*512*4);            // h  (mode1 out, fp32)
  float* xf = (float*)alloc((size_t)NN*512*4);            // gat out, fp32
  unsigned short* actH0 = (unsigned short*)alloc((size_t)NN*512*2);
  unsigned short* actL0 = (unsigned short*)alloc((size_t)NN*512*2);
  unsigned short* actH1 = (unsigned short*)alloc((size_t)NN*512*2);
  unsigned short* actL1 = (unsigned short*)alloc((size_t)NN*512*2);
  unsigned short* preH  = (unsigned short*)alloc((size_t)NN*256*2);
  unsigned short* preL  = (unsigned short*)alloc((size_t)NN*256*2);
  const int wK[7]  = {36, 128, 128, 256, 256, 512, 512};
  const int wM[7]  = {128, 128, 256, 256, 512, 512, 256};
  const int wKp[7] = {64, 128, 128, 256, 256, 512, 512};
  const float* wsrc[7] = {gw[0], aw[0], gw[1], aw[1], gw[2], aw[2], apw1};
  unsigned short* wTh[7]; unsigned short* wTl[7];
  for (int i = 0; i < 7; i++){
    size_t sz = (size_t)wM[i]*wKp[i]*2;
    wTh[i] = (unsigned short*)alloc(sz);
    wTl[i] = (unsigned short*)alloc(sz);
  }
  float* dinv = (float*)alloc(NN*4);
  float* as_  = (float*)alloc(NN*NH*4);
  float* ad_  = (float*)alloc(NN*NH*4);
  float* apre = (float*)alloc(NN*4);
  int* rowptr = (int*)alloc((NN+1)*4);
  int* colidx = (int*)alloc((size_t)NE*4);
  int* cnt    = (int*)alloc(NN*4);
  int* cursor = (int*)alloc(NN*4);
  int* starts = (int*)alloc((NB+1)*4);
  int* perm   = (int*)alloc(NN*4);

  // ---- conv descriptor (weights only) ----
  AllConv ac;
  int convTot = 0;
  for (int i = 0; i < 7; i++){
    ac.src[i] = wsrc[i]; ac.dh[i] = wTh[i]; ac.dl[i] = wTl[i];
    ac.K[i] = wK[i]; ac.Mm[i] = wM[i]; ac.Kp[i] = wKp[i];
    ac.tot[i] = wKp[i]*wM[i];
    convTot += ac.tot[i];
  }

  // ---- CSR build: memset -> parallel count+conv -> scan (cnt) -> fill ----
  hipMemsetAsync(cnt, 0, NN*sizeof(int), stream);
  int convBlks = (convTot + 255) / 256;
  k_count_conv<<<CNT_BLKS + convBlks, 256, 0, stream>>>(dst, cnt, ac, convTot);
  k_scan_all<<<1, 1024, 0, stream>>>(cnt, batch, rowptr, dinv, cursor, apre, starts, perm);
  k_fill<<<(NE+255)/256, 256, 0, stream>>>(src, dst, rowptr, cursor, colidx);

  const int dims[4] = {36, 128, 256, 512};
  const int ngrp = (NN + 15) / 16;
  int wi = 0;
  for (int i = 0; i < 3; i++){
    int Kin = (i == 0) ? 64 : dims[i];
    int M = dims[i+1], C = M/NH;
    int nchunk_in = Kin / 64;
    int nchunk = M / 64;
    int nblk = (M/GBN) * ((NN+GBM-1)/GBM);
    if (i == 0){
      k_gcn_pre0<<<ngrp, 256, 0, stream>>>(x0, dinv, rowptr, colidx, perm, preH, preL);
    } else {
      k_gcn_pre<<<nchunk_in*ngrp, 256, 0, stream>>>(xf, dinv, rowptr, colidx, perm,
                                                    preH, preL, Kin, nchunk_in);
    }
    k_gemm_bf3<<<nblk, 256, 0, stream>>>(preH, preL, wTh[wi], wTl[wi], hf, NN, wKp[wi], M,
                                         1, gb[i], actH0, actL0,
                                         nullptr, nullptr, nullptr, nullptr, C);
    wi++;
    k_gemm_bf3<<<nblk, 256, 0, stream>>>(actH0, actL0, wTh[wi], wTl[wi], f1, NN, wKp[wi], M,
                                         2, nullptr, nullptr, nullptr,
                                         asw[i], adw[i], as_, ad_, C);
    wi++;
    k_gat_gather<<<nchunk*ngrp, 256, 0, stream>>>(f1, hf, rowptr, colidx, perm,
                                                  as_, ad_, ab[i],
                                                  actH1, actL1, xf, M, C, nchunk,
                                                  (i == 2) ? 1 : 0);
  }

  // ---- pooling ----
  {
    int nblk = (256/GBN) * ((NN+GBM-1)/GBM);
    k_gemm_bf3<<<nblk, 256, 0, stream>>>(actH1, actL1, wTh[6], wTl[6], nullptr, NN, wKp[6], 256,
                                         3, apb1, nullptr, nullptr,
                                         apw2, nullptr, apre, nullptr, 64);
  }
  k_pool<<<NB*2, 512, 0, stream>>>(xf, apre, starts, out);
}

// Round 12
// 374.985 us; speedup vs baseline: 1.1832x; 1.0109x over previous
//
#include <hip/hip_runtime.h>
#include <math.h>

#define NN 10000
#define NE 160000
#define NB 128
#define NH 4
#define DOUT 512
#define NEG 0.2f
#define CNT_BLKS ((NE + 255) / 256)    // 625

typedef __attribute__((ext_vector_type(8))) short short8;
typedef __attribute__((ext_vector_type(4))) float f32x4;
typedef __attribute__((ext_vector_type(4))) unsigned short us4;

__device__ __forceinline__ float leakyf(float v){ return fmaxf(v, NEG*v); }
__device__ __forceinline__ void fma4(float4& a, const float4 v, float w){
  a.x += v.x*w; a.y += v.y*w; a.z += v.z*w; a.w += v.w*w;
}
__device__ __forceinline__ unsigned short f2bf(float f){
  unsigned int u = __float_as_uint(f);
  u += 0x7FFFu + ((u >> 16) & 1u);
  return (unsigned short)(u >> 16);
}
__device__ __forceinline__ float bf2f(unsigned short h){
  return __uint_as_float(((unsigned int)h) << 16);
}
__device__ __forceinline__ void split2(float v, unsigned short& h, unsigned short& l){
  h = f2bf(v);
  l = f2bf(v - bf2f(h));
}
__device__ __forceinline__ void store_hl(unsigned short* H, unsigned short* L,
                                         size_t base, float4 v){
  us4 h, l; unsigned short hh, ll;
  split2(v.x, hh, ll); h[0]=hh; l[0]=ll;
  split2(v.y, hh, ll); h[1]=hh; l[1]=ll;
  split2(v.z, hh, ll); h[2]=hh; l[2]=ll;
  split2(v.w, hh, ll); h[3]=hh; l[3]=ll;
  *(us4*)&H[base] = h;
  *(us4*)&L[base] = l;
}
__device__ __forceinline__ void gl_lds16(const unsigned short* g, unsigned short* l){
  __builtin_amdgcn_global_load_lds(
      (const __attribute__((address_space(1))) unsigned int*)g,
      (__attribute__((address_space(3))) unsigned int*)l, 16, 0, 0);
}

// ============ conversions descriptor (weights only; x0 handled by k_gcn_pre0) ============
struct AllConv {
  const float* src[7];
  unsigned short* dh[7];
  unsigned short* dl[7];
  int K[7], Mm[7], Kp[7], tot[7];
};

// ===== merged: edge count (blocks [0,CNT_BLKS)) + weight conversions (rest) =====
__global__ void k_count_conv(const int* __restrict__ dst, int* __restrict__ cnt,
                             AllConv a, int convTot){
  int bid = blockIdx.x;
  if (bid < CNT_BLKS){
    int e = bid*256 + threadIdx.x;
    if (e < NE) atomicAdd(&cnt[dst[e]], 1);
  } else {
    int idx = (bid - CNT_BLKS)*256 + threadIdx.x;
    if (idx >= convTot) return;
    int j = 0;
    while (idx >= a.tot[j]){ idx -= a.tot[j]; j++; }
    int Kp = a.Kp[j], K = a.K[j], M = a.Mm[j];
    int kk = idx % Kp, m = idx / Kp;
    float v = (kk < K) ? a.src[j][(size_t)kk*M + m] : 0.f;
    unsigned short h, l; split2(v, h, l);
    a.dh[j][idx] = h; a.dl[j][idx] = l;
  }
}

// ===== single-block scan: rowptr/dinv/cursor/apre/starts + degree-sorted perm =====
__global__ __launch_bounds__(1024) void k_scan_all(
    const int* __restrict__ cnt, const int* __restrict__ batch,
    int* __restrict__ rowptr, float* __restrict__ dinv,
    int* __restrict__ cursor, float* __restrict__ apre,
    int* __restrict__ starts, int* __restrict__ perm){
  __shared__ int sh[NN];      // 40 KB
  __shared__ int pref[1024];
  __shared__ int hist[512];
  __shared__ int hbase[512];
  int t = threadIdx.x;
  for (int i = t; i < NN; i += 1024) sh[i] = cnt[i];
  if (t < 512) hist[t] = 0;
  if (t <= NB){
    int lo = 0, hi = NN;
    while (lo < hi){ int mid = (lo + hi) >> 1; if (batch[mid] < t) lo = mid + 1; else hi = mid; }
    starts[t] = lo;
  }
  __syncthreads();
  int base = t*10;
  int csum = 0;
#pragma unroll
  for (int k = 0; k < 10; k++){
    int i = base + k;
    if (i < NN){
      csum += sh[i];
      atomicAdd(&hist[511 - min(sh[i], 511)], 1);   // descending degree bins
    }
  }
  pref[t] = csum; __syncthreads();     // histogram + csum complete
  int horig = (t < 512) ? hist[t] : 0;
  for (int o = 1; o < 1024; o <<= 1){
    int v = (t >= o) ? pref[t - o] : 0;
    __syncthreads();
    pref[t] += v;
    __syncthreads();
  }
  for (int o = 1; o < 512; o <<= 1){
    int v = 0;
    if (t < 512 && t >= o) v = hist[t - o];
    __syncthreads();
    if (t < 512 && t >= o) hist[t] += v;
    __syncthreads();
  }
  if (t < 512) hbase[t] = hist[t] - horig;   // exclusive prefix -> scatter cursor
  __syncthreads();
  int run = pref[t] - csum;   // exclusive prefix of degrees
#pragma unroll
  for (int k = 0; k < 10; k++){
    int i = base + k;
    if (i < NN){
      int c = sh[i];
      rowptr[i] = run;
      run += c;
      dinv[i] = rsqrtf((float)c + 1.f);
      cursor[i] = 0;
      apre[i] = 0.f;
      int pos = atomicAdd(&hbase[511 - min(c, 511)], 1);
      perm[pos] = i;
    }
  }
  if (t == 1023) rowptr[NN] = pref[1023];
}

__global__ void k_fill(const int* __restrict__ src, const int* __restrict__ dst,
                       const int* __restrict__ rowptr, int* __restrict__ cursor,
                       int* __restrict__ colidx){
  int e = blockIdx.x*blockDim.x + threadIdx.x;
  if (e >= NE) return;
  int d = dst[e];
  int pos = atomicAdd(&cursor[d], 1);
  colidx[rowptr[d] + pos] = src[e];
}

// ===== GEMM: C[N,M] = (Ah+Al)[N,Kp] @ (Bh+Bl)^T, bf16x3, K-step 64 =====
#define GBM 64
#define GBN 128
#define GBK 64
__global__ __launch_bounds__(256) void k_gemm_bf3(
    const unsigned short* __restrict__ Ah, const unsigned short* __restrict__ Al,
    const unsigned short* __restrict__ Bh, const unsigned short* __restrict__ Bl,
    float* __restrict__ C, int N, int Kp, int M, int mode,
    const float* __restrict__ bias, unsigned short* __restrict__ outH,
    unsigned short* __restrict__ outL,
    const float* __restrict__ a_s, const float* __restrict__ a_d,
    float* __restrict__ as_o, float* __restrict__ ad_o, int Cdim){
  __shared__ unsigned short AsH[2*GBM*32], AsL[2*GBM*32];
  __shared__ unsigned short BsH[2*GBN*32], BsL[2*GBN*32];
  __shared__ float sred[2][GBM][4];
  int gx = M / GBN;
  int gy = (N + GBM - 1) / GBM;
  const int G = 8;
  int bid = blockIdx.x;
  int full = gy / G;
  int bid_full = full * G * gx;
  int by, bx;
  if (bid < bid_full){
    int g = bid / (G*gx); int rem = bid % (G*gx);
    by = g*G + rem % G; bx = rem / G;
  } else {
    int rem = bid - bid_full; int rows = gy - full*G;
    by = full*G + rem % rows; bx = rem / rows;
  }
  int row0 = by * GBM, col0 = bx * GBN;
  int t = threadIdx.x;
  int w = t >> 6, L = t & 63;
  int lm = L & 15, lq = L >> 4;
  int wc = w * 32;

  int sr = L >> 2, sc = L & 3;
  int art = w*16 + sr;
  int ga  = (sc - ((art >> 1) & 3)) & 3;
  int agrow = min(row0 + art, N-1);
  int brt0 = w*16 + sr;
  int brt1 = (w+4)*16 + sr;
  int gb0 = (sc - ((brt0 >> 1) & 3)) & 3;
  int gb1 = (sc - ((brt1 >> 1) & 3)) & 3;
  int bgrow0 = col0 + brt0, bgrow1 = col0 + brt1;

  int rc = (lq + (lm >> 1)) & 3;
  int aoff[4], boff[2];
#pragma unroll
  for (int mi = 0; mi < 4; mi++) aoff[mi] = (mi*16 + lm)*32 + rc*8;
#pragma unroll
  for (int ni = 0; ni < 2; ni++) boff[ni] = (wc + ni*16 + lm)*32 + rc*8;

  f32x4 acc[4][2];
#pragma unroll
  for (int i = 0; i < 4; i++)
#pragma unroll
    for (int j = 0; j < 2; j++) acc[i][j] = (f32x4){0.f,0.f,0.f,0.f};

  int nk = Kp / GBK;
  for (int kt = 0; kt < nk; kt++){
    int k0 = kt * GBK;
    if (kt) __syncthreads();
#pragma unroll
    for (int h = 0; h < 2; h++){
      int kh = k0 + h*32;
      gl_lds16(&Ah[(size_t)agrow*Kp + kh + ga*8],  &AsH[h*2048 + w*512]);
      gl_lds16(&Al[(size_t)agrow*Kp + kh + ga*8],  &AsL[h*2048 + w*512]);
      gl_lds16(&Bh[(size_t)bgrow0*Kp + kh + gb0*8], &BsH[h*4096 + w*512]);
      gl_lds16(&Bh[(size_t)bgrow1*Kp + kh + gb1*8], &BsH[h*4096 + (w+4)*512]);
      gl_lds16(&Bl[(size_t)bgrow0*Kp + kh + gb0*8], &BsL[h*4096 + w*512]);
      gl_lds16(&Bl[(size_t)bgrow1*Kp + kh + gb1*8], &BsL[h*4096 + (w+4)*512]);
    }
    __syncthreads();

#pragma unroll
    for (int h = 0; h < 2; h++){
      short8 ah[4], al[4], bh[2], bl[2];
#pragma unroll
      for (int mi = 0; mi < 4; mi++){
        ah[mi] = *(const short8*)&AsH[h*2048 + aoff[mi]];
        al[mi] = *(const short8*)&AsL[h*2048 + aoff[mi]];
      }
#pragma unroll
      for (int ni = 0; ni < 2; ni++){
        bh[ni] = *(const short8*)&BsH[h*4096 + boff[ni]];
        bl[ni] = *(const short8*)&BsL[h*4096 + boff[ni]];
      }
#pragma unroll
      for (int mi = 0; mi < 4; mi++)
#pragma unroll
        for (int ni = 0; ni < 2; ni++){
          acc[mi][ni] = __builtin_amdgcn_mfma_f32_16x16x32_bf16(ah[mi], bh[ni], acc[mi][ni], 0, 0, 0);
          acc[mi][ni] = __builtin_amdgcn_mfma_f32_16x16x32_bf16(ah[mi], bl[ni], acc[mi][ni], 0, 0, 0);
          acc[mi][ni] = __builtin_amdgcn_mfma_f32_16x16x32_bf16(al[mi], bh[ni], acc[mi][ni], 0, 0, 0);
        }
    }
  }
  if (mode == 1){
    // relu + bias; store H/L (GEMM2 A-operand) AND fp32 copy (gat residual read)
#pragma unroll
    for (int mi = 0; mi < 4; mi++)
#pragma unroll
      for (int ni = 0; ni < 2; ni++){
#pragma unroll
        for (int r = 0; r < 4; r++){
          int row = row0 + mi*16 + lq*4 + r;
          int col = col0 + wc + ni*16 + lm;
          if (row < N){
            float v = fmaxf(acc[mi][ni][r] + bias[col], 0.f);
            unsigned short hh, ll; split2(v, hh, ll);
            outH[(size_t)row*M + col] = hh;
            outL[(size_t)row*M + col] = ll;
            C[(size_t)row*M + col] = v;
          }
        }
      }
  } else if (mode != 3){
#pragma unroll
    for (int mi = 0; mi < 4; mi++)
#pragma unroll
      for (int ni = 0; ni < 2; ni++){
#pragma unroll
        for (int r = 0; r < 4; r++){
          int row = row0 + mi*16 + lq*4 + r;
          int col = col0 + wc + ni*16 + lm;
          if (row < N) C[(size_t)row*M + col] = acc[mi][ni][r];
        }
      }
  }
  if (mode == 2){
    float sA0 = a_s[col0 + wc + lm], sA1 = a_s[col0 + wc + 16 + lm];
    float dA0 = a_d[col0 + wc + lm], dA1 = a_d[col0 + wc + 16 + lm];
#pragma unroll
    for (int mi = 0; mi < 4; mi++)
#pragma unroll
      for (int r = 0; r < 4; r++){
        float vs = acc[mi][0][r]*sA0 + acc[mi][1][r]*sA1;
        float vd = acc[mi][0][r]*dA0 + acc[mi][1][r]*dA1;
#pragma unroll
        for (int o = 1; o <= 8; o <<= 1){
          vs += __shfl_xor(vs, o);
          vd += __shfl_xor(vd, o);
        }
        if (lm == 0){
          int row = mi*16 + lq*4 + r;
          sred[0][row][w] = vs;
          sred[1][row][w] = vd;
        }
      }
    __syncthreads();
    if (t < GBM){
      int n = row0 + t;
      if (n < N){
        int wph = Cdim >> 5;
        int nheads = 4 / wph;
        for (int g = 0; g < nheads; g++){
          float ss = 0.f, dd = 0.f;
          for (int q = 0; q < wph; q++){
            ss += sred[0][t][g*wph + q];
            dd += sred[1][t][g*wph + q];
          }
          int hd = (col0 + g*wph*32) / Cdim;
          as_o[n*NH + hd] = ss;
          ad_o[n*NH + hd] = dd;
        }
      }
    }
  } else if (mode == 3){
    float b0 = bias[col0 + wc + lm], b1v = bias[col0 + wc + 16 + lm];
    float w0v = a_s[col0 + wc + lm], w1v = a_s[col0 + wc + 16 + lm];
#pragma unroll
    for (int mi = 0; mi < 4; mi++)
#pragma unroll
      for (int r = 0; r < 4; r++){
        float v = tanhf(acc[mi][0][r] + b0)*w0v + tanhf(acc[mi][1][r] + b1v)*w1v;
#pragma unroll
        for (int o = 1; o <= 8; o <<= 1) v += __shfl_xor(v, o);
        if (lm == 0) sred[0][mi*16 + lq*4 + r][w] = v;
      }
    __syncthreads();
    if (t < GBM){
      int n = row0 + t;
      if (n < N){
        float s = sred[0][t][0] + sred[0][t][1] + sred[0][t][2] + sred[0][t][3];
        atomicAdd(&as_o[n], s);
      }
    }
  }
}

// ===== GCN pre-agg layer 0: fp32 x0 direct, 8-way, degree-sorted =====
__global__ __launch_bounds__(256) void k_gcn_pre0(
    const float* __restrict__ x0, const float* __restrict__ dinv,
    const int* __restrict__ rowptr, const int* __restrict__ colidx,
    const int* __restrict__ perm,
    unsigned short* __restrict__ outH, unsigned short* __restrict__ outL){
  int t = threadIdx.x;
  int sub = t & 15;
  int gid = blockIdx.x*16 + (t >> 4);
  if (gid >= NN) return;
  int n = perm[gid];
  int f0 = sub*4;
  bool act = f0 < 36;
  int b = rowptr[n], e = rowptr[n+1];
  float dn = dinv[n];
  float4 a0 = make_float4(0,0,0,0), a1 = make_float4(0,0,0,0);
  float4 a2 = make_float4(0,0,0,0), a3 = make_float4(0,0,0,0);
  if (act){
    float4 sv = *(const float4*)&x0[(size_t)n*36 + f0];
    int j = b;
    for (; j + 7 < e; j += 8){
      int s0 = colidx[j],   s1 = colidx[j+1], s2 = colidx[j+2], s3 = colidx[j+3];
      int s4 = colidx[j+4], s5 = colidx[j+5], s6 = colidx[j+6], s7 = colidx[j+7];
      float w0 = dinv[s0], w1 = dinv[s1], w2 = dinv[s2], w3 = dinv[s3];
      float w4 = dinv[s4], w5 = dinv[s5], w6 = dinv[s6], w7 = dinv[s7];
      float4 v0 = *(const float4*)&x0[(size_t)s0*36 + f0];
      float4 v1 = *(const float4*)&x0[(size_t)s1*36 + f0];
      float4 v2 = *(const float4*)&x0[(size_t)s2*36 + f0];
      float4 v3 = *(const float4*)&x0[(size_t)s3*36 + f0];
      float4 v4 = *(const float4*)&x0[(size_t)s4*36 + f0];
      float4 v5 = *(const float4*)&x0[(size_t)s5*36 + f0];
      float4 v6 = *(const float4*)&x0[(size_t)s6*36 + f0];
      float4 v7 = *(const float4*)&x0[(size_t)s7*36 + f0];
      fma4(a0, v0, w0*dn); fma4(a1, v1, w1*dn);
      fma4(a2, v2, w2*dn); fma4(a3, v3, w3*dn);
      fma4(a0, v4, w4*dn); fma4(a1, v5, w5*dn);
      fma4(a2, v6, w6*dn); fma4(a3, v7, w7*dn);
    }
    for (; j + 3 < e; j += 4){
      int s0 = colidx[j], s1 = colidx[j+1], s2 = colidx[j+2], s3 = colidx[j+3];
      float w0 = dinv[s0], w1 = dinv[s1], w2 = dinv[s2], w3 = dinv[s3];
      float4 v0 = *(const float4*)&x0[(size_t)s0*36 + f0];
      float4 v1 = *(const float4*)&x0[(size_t)s1*36 + f0];
      float4 v2 = *(const float4*)&x0[(size_t)s2*36 + f0];
      float4 v3 = *(const float4*)&x0[(size_t)s3*36 + f0];
      fma4(a0, v0, w0*dn); fma4(a1, v1, w1*dn);
      fma4(a2, v2, w2*dn); fma4(a3, v3, w3*dn);
    }
    for (; j < e; j++){
      int s = colidx[j];
      float4 v = *(const float4*)&x0[(size_t)s*36 + f0];
      fma4(a0, v, dinv[s]*dn);
    }
    float4 acc = make_float4(a0.x+a1.x+a2.x+a3.x, a0.y+a1.y+a2.y+a3.y,
                             a0.z+a1.z+a2.z+a3.z, a0.w+a1.w+a2.w+a3.w);
    float dn2 = dn*dn;
    acc.x += sv.x*dn2; acc.y += sv.y*dn2; acc.z += sv.z*dn2; acc.w += sv.w*dn2;
    store_hl(outH, outL, (size_t)n*64 + f0, acc);
  } else {
    store_hl(outH, outL, (size_t)n*64 + f0, make_float4(0,0,0,0));
  }
}

// ===== GCN pre-agg (layers 1..2): fp32 input (xf), 8-way, degree-sorted =====
__global__ __launch_bounds__(256) void k_gcn_pre(
    const float* __restrict__ xf, const float* __restrict__ dinv,
    const int* __restrict__ rowptr, const int* __restrict__ colidx,
    const int* __restrict__ perm,
    unsigned short* __restrict__ outH, unsigned short* __restrict__ outL,
    int Kp, int nchunk){
  int bid = blockIdx.x;
  int chunk = bid % nchunk, grp = bid / nchunk;
  int t = threadIdx.x;
  int sub = t & 15;
  int gid = grp*16 + (t >> 4);
  if (gid >= NN) return;
  int n = perm[gid];
  int f0 = chunk*64 + sub*4;
  int b = rowptr[n], e = rowptr[n+1];
  float dn = dinv[n];
  float4 sv = *(const float4*)&xf[(size_t)n*Kp + f0];
  float4 a0 = make_float4(0,0,0,0), a1 = make_float4(0,0,0,0);
  float4 a2 = make_float4(0,0,0,0), a3 = make_float4(0,0,0,0);
  int j = b;
  for (; j + 7 < e; j += 8){
    int s0 = colidx[j],   s1 = colidx[j+1], s2 = colidx[j+2], s3 = colidx[j+3];
    int s4 = colidx[j+4], s5 = colidx[j+5], s6 = colidx[j+6], s7 = colidx[j+7];
    float w0 = dinv[s0], w1 = dinv[s1], w2 = dinv[s2], w3 = dinv[s3];
    float w4 = dinv[s4], w5 = dinv[s5], w6 = dinv[s6], w7 = dinv[s7];
    float4 v0 = *(const float4*)&xf[(size_t)s0*Kp + f0];
    float4 v1 = *(const float4*)&xf[(size_t)s1*Kp + f0];
    float4 v2 = *(const float4*)&xf[(size_t)s2*Kp + f0];
    float4 v3 = *(const float4*)&xf[(size_t)s3*Kp + f0];
    float4 v4 = *(const float4*)&xf[(size_t)s4*Kp + f0];
    float4 v5 = *(const float4*)&xf[(size_t)s5*Kp + f0];
    float4 v6 = *(const float4*)&xf[(size_t)s6*Kp + f0];
    float4 v7 = *(const float4*)&xf[(size_t)s7*Kp + f0];
    fma4(a0, v0, w0*dn); fma4(a1, v1, w1*dn);
    fma4(a2, v2, w2*dn); fma4(a3, v3, w3*dn);
    fma4(a0, v4, w4*dn); fma4(a1, v5, w5*dn);
    fma4(a2, v6, w6*dn); fma4(a3, v7, w7*dn);
  }
  for (; j + 3 < e; j += 4){
    int s0 = colidx[j], s1 = colidx[j+1], s2 = colidx[j+2], s3 = colidx[j+3];
    float w0 = dinv[s0], w1 = dinv[s1], w2 = dinv[s2], w3 = dinv[s3];
    float4 v0 = *(const float4*)&xf[(size_t)s0*Kp + f0];
    float4 v1 = *(const float4*)&xf[(size_t)s1*Kp + f0];
    float4 v2 = *(const float4*)&xf[(size_t)s2*Kp + f0];
    float4 v3 = *(const float4*)&xf[(size_t)s3*Kp + f0];
    fma4(a0, v0, w0*dn); fma4(a1, v1, w1*dn);
    fma4(a2, v2, w2*dn); fma4(a3, v3, w3*dn);
  }
  for (; j < e; j++){
    int s = colidx[j];
    float4 v = *(const float4*)&xf[(size_t)s*Kp + f0];
    fma4(a0, v, dinv[s]*dn);
  }
  float4 acc = make_float4(a0.x+a1.x+a2.x+a3.x, a0.y+a1.y+a2.y+a3.y,
                           a0.z+a1.z+a2.z+a3.z, a0.w+a1.w+a2.w+a3.w);
  float dn2 = dn*dn;
  acc.x += sv.x*dn2; acc.y += sv.y*dn2; acc.z += sv.z*dn2; acc.w += sv.w*dn2;
  store_hl(outH, outL, (size_t)n*Kp + f0, acc);
}

// ===== GAT gather: fixed-shift softmax, fp32 residual, degree-sorted =====
__global__ __launch_bounds__(256) void k_gat_gather(
    const float* __restrict__ hg, const float* __restrict__ hf,
    const int* __restrict__ rowptr, const int* __restrict__ colidx,
    const int* __restrict__ perm,
    const float* __restrict__ as_, const float* __restrict__ ad_,
    const float* __restrict__ ab,
    unsigned short* __restrict__ outH, unsigned short* __restrict__ outL,
    float* __restrict__ xf,
    int M, int C, int nchunk){
  int bid = blockIdx.x;
  int chunk = bid % nchunk, grp = bid / nchunk;
  int t = threadIdx.x;
  int sub = t & 15;
  int gid = grp*16 + (t >> 4);
  if (gid >= NN) return;
  int n = perm[gid];
  int f0 = chunk*64 + sub*4;
  int hd = f0 / C;
  int b = rowptr[n], e = rowptr[n+1];
  int ai = n*NH + hd;
  float adn = ad_[ai];
  float sl = fminf(fmaxf(leakyf(as_[ai] + adn), -80.f), 80.f);
  float es = __expf(sl);
  // hoisted tail loads — latency hides under the edge loop
  float4 sv = *(const float4*)&hg[(size_t)n*M + f0];
  float4 hv = *(const float4*)&hf[(size_t)n*M + f0];
  float4 bb = *(const float4*)&ab[f0];
  float d = es;
  float4 a0 = make_float4(0,0,0,0), a1 = make_float4(0,0,0,0);
  float4 a2 = make_float4(0,0,0,0), a3 = make_float4(0,0,0,0);
  int j = b;
  for (; j + 7 < e; j += 8){
    int s0 = colidx[j],   s1 = colidx[j+1], s2 = colidx[j+2], s3 = colidx[j+3];
    int s4 = colidx[j+4], s5 = colidx[j+5], s6 = colidx[j+6], s7 = colidx[j+7];
    float l0 = leakyf(as_[s0*NH + hd] + adn), l1 = leakyf(as_[s1*NH + hd] + adn);
    float l2 = leakyf(as_[s2*NH + hd] + adn), l3 = leakyf(as_[s3*NH + hd] + adn);
    float l4 = leakyf(as_[s4*NH + hd] + adn), l5 = leakyf(as_[s5*NH + hd] + adn);
    float l6 = leakyf(as_[s6*NH + hd] + adn), l7 = leakyf(as_[s7*NH + hd] + adn);
    float4 v0 = *(const float4*)&hg[(size_t)s0*M + f0];
    float4 v1 = *(const float4*)&hg[(size_t)s1*M + f0];
    float4 v2 = *(const float4*)&hg[(size_t)s2*M + f0];
    float4 v3 = *(const float4*)&hg[(size_t)s3*M + f0];
    float4 v4 = *(const float4*)&hg[(size_t)s4*M + f0];
    float4 v5 = *(const float4*)&hg[(size_t)s5*M + f0];
    float4 v6 = *(const float4*)&hg[(size_t)s6*M + f0];
    float4 v7 = *(const float4*)&hg[(size_t)s7*M + f0];
    float w0 = __expf(fminf(fmaxf(l0,-80.f),80.f)), w1 = __expf(fminf(fmaxf(l1,-80.f),80.f));
    float w2 = __expf(fminf(fmaxf(l2,-80.f),80.f)), w3 = __expf(fminf(fmaxf(l3,-80.f),80.f));
    float w4 = __expf(fminf(fmaxf(l4,-80.f),80.f)), w5 = __expf(fminf(fmaxf(l5,-80.f),80.f));
    float w6 = __expf(fminf(fmaxf(l6,-80.f),80.f)), w7 = __expf(fminf(fmaxf(l7,-80.f),80.f));
    d += ((w0 + w1) + (w2 + w3)) + ((w4 + w5) + (w6 + w7));
    fma4(a0, v0, w0); fma4(a1, v1, w1);
    fma4(a2, v2, w2); fma4(a3, v3, w3);
    fma4(a0, v4, w4); fma4(a1, v5, w5);
    fma4(a2, v6, w6); fma4(a3, v7, w7);
  }
  for (; j < e; j++){
    int s = colidx[j];
    float l = leakyf(as_[s*NH + hd] + adn);
    float4 v = *(const float4*)&hg[(size_t)s*M + f0];
    float ww = __expf(fminf(fmaxf(l,-80.f),80.f));
    d += ww;
    fma4(a0, v, ww);
  }
  float4 acc = make_float4(a0.x+a1.x+a2.x+a3.x, a0.y+a1.y+a2.y+a3.y,
                           a0.z+a1.z+a2.z+a3.z, a0.w+a1.w+a2.w+a3.w);
  float inv = 1.f/d;
  float4 r = make_float4(
    hv.x + bb.x + (sv.x*es + acc.x)*inv,
    hv.y + bb.y + (sv.y*es + acc.y)*inv,
    hv.z + bb.z + (sv.z*es + acc.z)*inv,
    hv.w + bb.w + (sv.w*es + acc.w)*inv);
  *(float4*)&xf[(size_t)n*M + f0] = r;
  store_hl(outH, outL, (size_t)n*M + f0, r);
}

// ====== attention pooling: 2 blocks/graph (feature halves), 8-way node slice ======
__global__ __launch_bounds__(512) void k_pool(
    const float* __restrict__ xf,
    const float* __restrict__ apre, const int* __restrict__ starts,
    float* __restrict__ out){
  __shared__ float red[512];
  __shared__ float4 comb[3][8][64];   // 24 KB
  int g = blockIdx.x >> 1, half = blockIdx.x & 1;
  int t = threadIdx.x;
  int b = starts[g], e = starts[g+1];
  float m = -INFINITY;
  for (int n = b + t; n < e; n += 512) m = fmaxf(m, apre[n]);
  red[t] = m; __syncthreads();
  for (int o = 256; o > 0; o >>= 1){
    if (t < o) red[t] = fmaxf(red[t], red[t + o]);
    __syncthreads();
  }
  m = red[0]; __syncthreads();
  float s = 0.f;
  for (int n = b + t; n < e; n += 512) s += __expf(apre[n] - m);
  red[t] = s; __syncthreads();
  for (int o = 256; o > 0; o >>= 1){
    if (t < o) red[t] += red[t + o];
    __syncthreads();
  }
  float inv = 1.f / (red[0] + 1e-8f);
  int lf = t & 63, sl = t >> 6;          // 64 float4 feats × 8 node-slices
  int fo = half*64 + lf;                 // float4 index in [0,128)
  float4 sum = make_float4(0,0,0,0), wacc = make_float4(0,0,0,0);
  float4 mx = make_float4(-INFINITY,-INFINITY,-INFINITY,-INFINITY);
  for (int n = b + sl; n < e; n += 8){
    float4 xv = *(const float4*)&xf[(size_t)n*DOUT + fo*4];
    float p = __expf(apre[n] - m) * inv;
    sum.x += xv.x; sum.y += xv.y; sum.z += xv.z; sum.w += xv.w;
    mx.x = fmaxf(mx.x, xv.x); mx.y = fmaxf(mx.y, xv.y);
    mx.z = fmaxf(mx.z, xv.z); mx.w = fmaxf(mx.w, xv.w);
    fma4(wacc, xv, p);
  }
  comb[0][sl][lf] = wacc; comb[1][sl][lf] = sum; comb[2][sl][lf] = mx;
  __syncthreads();
  if (sl == 0){
#pragma unroll
    for (int q = 1; q < 8; q++){
      float4 w2 = comb[0][q][lf], s2 = comb[1][q][lf], m2 = comb[2][q][lf];
      wacc.x += w2.x; wacc.y += w2.y; wacc.z += w2.z; wacc.w += w2.w;
      sum.x += s2.x; sum.y += s2.y; sum.z += s2.z; sum.w += s2.w;
      mx.x = fmaxf(mx.x, m2.x); mx.y = fmaxf(mx.y, m2.y);
      mx.z = fmaxf(mx.z, m2.z); mx.w = fmaxf(mx.w, m2.w);
    }
    float ic = 1.f / fmaxf((float)(e - b), 1.f);
    float4* o = (float4*)(out + (size_t)g*4*DOUT);
    o[fo]       = wacc;
    o[128 + fo] = make_float4(sum.x*ic, sum.y*ic, sum.z*ic, sum.w*ic);
    o[256 + fo] = mx;
    o[384 + fo] = sum;
  }
}

extern "C" void kernel_launch(void* const* d_in, const int* in_sizes, int n_in,
                              void* d_out, int out_size, void* d_ws, size_t ws_size,
                              hipStream_t stream) {
  const float* x0   = (const float*)d_in[0];
  const int*   ei   = (const int*)d_in[1];
  const int*   src  = ei;
  const int*   dst  = ei + NE;
  const int*   batch= (const int*)d_in[2];
  const float* gw[3]  = {(const float*)d_in[3],  (const float*)d_in[9],  (const float*)d_in[15]};
  const float* gb[3]  = {(const float*)d_in[4],  (const float*)d_in[10], (const float*)d_in[16]};
  const float* aw[3]  = {(const float*)d_in[5],  (const float*)d_in[11], (const float*)d_in[17]};
  const float* asw[3] = {(const float*)d_in[6],  (const float*)d_in[12], (const float*)d_in[18]};
  const float* adw[3] = {(const float*)d_in[7],  (const float*)d_in[13], (const float*)d_in[19]};
  const float* ab[3]  = {(const float*)d_in[8],  (const float*)d_in[14], (const float*)d_in[20]};
  const float* apw1 = (const float*)d_in[21];
  const float* apb1 = (const float*)d_in[22];
  const float* apw2 = (const float*)d_in[23];
  float* out = (float*)d_out;

  // ---- workspace carve ----
  char* p = (char*)d_ws;
  auto alloc = [&](size_t bytes) -> void* {
    void* r = (void*)p; p += (bytes + 255) & ~(size_t)255; return r;
  };
  float* f1 = (float*)alloc((size_t)NN*512*4);            // hg (mode2 out, fp32)
  float* hf = (float*)alloc((size_t)NN*512*4);            // h  (mode1 out, fp32)
  float* xf = (float*)alloc((size_t)NN*512*4);            // gat out, fp32
  unsigned short* actH0 = (unsigned short*)alloc((size_t)NN*512*2);
  unsigned short* actL0 = (unsigned short*)alloc((size_t)NN*512*2);
  unsigned short* actH1 = (unsigned short*)alloc((size_t)NN*512*2);
  unsigned short* actL1 = (unsigned short*)alloc((size_t)NN*512*2);
  unsigned short* preH  = (unsigned short*)alloc((size_t)NN*256*2);
  unsigned short* preL  = (unsigned short*)alloc((size_t)NN*256*2);
  const int wK[7]  = {36, 128, 128, 256, 256, 512, 512};
  const int wM[7]  = {128, 128, 256, 256, 512, 512, 256};
  const int wKp[7] = {64, 128, 128, 256, 256, 512, 512};
  const float* wsrc[7] = {gw[0], aw[0], gw[1], aw[1], gw[2], aw[2], apw1};
  unsigned short* wTh[7]; unsigned short* wTl[7];
  for (int i = 0; i < 7; i++){
    size_t sz = (size_t)wM[i]*wKp[i]*2;
    wTh[i] = (unsigned short*)alloc(sz);
    wTl[i] = (unsigned short*)alloc(sz);
  }
  float* dinv = (float*)alloc(NN*4);
  float* as_  = (float*)alloc(NN*NH*4);
  float* ad_  = (float*)alloc(NN*NH*4);
  float* apre = (float*)alloc(NN*4);
  int* rowptr = (int*)alloc((NN+1)*4);
  int* colidx = (int*)alloc((size_t)NE*4);
  int* cnt    = (int*)alloc(NN*4);
  int* cursor = (int*)alloc(NN*4);
  int* starts = (int*)alloc((NB+1)*4);
  int* perm   = (int*)alloc(NN*4);

  // ---- conv descriptor (weights only) ----
  AllConv ac;
  int convTot = 0;
  for (int i = 0; i < 7; i++){
    ac.src[i] = wsrc[i]; ac.dh[i] = wTh[i]; ac.dl[i] = wTl[i];
    ac.K[i] = wK[i]; ac.Mm[i] = wM[i]; ac.Kp[i] = wKp[i];
    ac.tot[i] = wKp[i]*wM[i];
    convTot += ac.tot[i];
  }

  // ---- CSR build (count merged with conversions) -> single-block scan -> fill ----
  hipMemsetAsync(cnt, 0, NN*sizeof(int), stream);
  int convBlks = (convTot + 255) / 256;
  k_count_conv<<<CNT_BLKS + convBlks, 256, 0, stream>>>(dst, cnt, ac, convTot);
  k_scan_all<<<1, 1024, 0, stream>>>(cnt, batch, rowptr, dinv, cursor, apre, starts, perm);
  k_fill<<<(NE+255)/256, 256, 0, stream>>>(src, dst, rowptr, cursor, colidx);

  const int dims[4] = {36, 128, 256, 512};
  const int ngrp = (NN + 15) / 16;
  int wi = 0;
  for (int i = 0; i < 3; i++){
    int Kin = (i == 0) ? 64 : dims[i];
    int M = dims[i+1], C = M/NH;
    int nchunk_in = Kin / 64;
    int nchunk = M / 64;
    int nblk = (M/GBN) * ((NN+GBM-1)/GBM);
    if (i == 0){
      k_gcn_pre0<<<ngrp, 256, 0, stream>>>(x0, dinv, rowptr, colidx, perm, preH, preL);
    } else {
      k_gcn_pre<<<nchunk_in*ngrp, 256, 0, stream>>>(xf, dinv, rowptr, colidx, perm,
                                                    preH, preL, Kin, nchunk_in);
    }
    k_gemm_bf3<<<nblk, 256, 0, stream>>>(preH, preL, wTh[wi], wTl[wi], hf, NN, wKp[wi], M,
                                         1, gb[i], actH0, actL0,
                                         nullptr, nullptr, nullptr, nullptr, C);
    wi++;
    k_gemm_bf3<<<nblk, 256, 0, stream>>>(actH0, actL0, wTh[wi], wTl[wi], f1, NN, wKp[wi], M,
                                         2, nullptr, nullptr, nullptr,
                                         asw[i], adw[i], as_, ad_, C);
    wi++;
    k_gat_gather<<<nchunk*ngrp, 256, 0, stream>>>(f1, hf, rowptr, colidx, perm,
                                                  as_, ad_, ab[i],
                                                  actH1, actL1, xf, M, C, nchunk);
  }

  // ---- pooling ----
  {
    int nblk = (256/GBN) * ((NN+GBM-1)/GBM);
    k_gemm_bf3<<<nblk, 256, 0, stream>>>(actH1, actL1, wTh[6], wTl[6], nullptr, NN, wKp[6], 256,
                                         3, apb1, nullptr, nullptr,
                                         apw2, nullptr, apre, nullptr, 64);
  }
  k_pool<<<NB*2, 512, 0, stream>>>(xf, apre, starts, out);
}